// Round 2
// baseline (708.551 us; speedup 1.0000x reference)
//
#include <hip/hip_runtime.h>
#include <math.h>

#define BB 4
#define TT 2048
#define EE 384
#define HH 6
#define DD 64
#define MM (BB*TT)   // 8192 tokens

// ---------------- tiled GEMM: C[m,n] = A[m,:] . W[n,:] (+bias, relu) ----------------
// A fp32 [M,384], W fp32 [N,384] (row n = output feature). Tile 64(m) x 128(n),
// BK=16, 256 thr, 4x8 micro-tile per thread.
__global__ __launch_bounds__(256) void k_gemm(const float* __restrict__ A,
                                              const float* __restrict__ W,
                                              const float* __restrict__ bias,
                                              float* __restrict__ Cout,
                                              int relu, int qlayout)
{
    __shared__ float As[16][68];     // [k][m]
    __shared__ float Bs[16][136];    // [k][n]
    const int m0 = blockIdx.x * 64;
    const int n0 = blockIdx.y * 128;
    const int tid = threadIdx.x;
    const int my = tid & 15;         // rows my*4..+3
    const int nx = tid >> 4;         // cols nx*8..+7
    float acc[4][8];
    #pragma unroll
    for (int i = 0; i < 4; i++)
        #pragma unroll
        for (int j = 0; j < 8; j++) acc[i][j] = 0.0f;

    const int alr = tid >> 2;        // 0..63
    const int alk = (tid & 3) * 4;   // 0,4,8,12
    const int blr = tid >> 1;        // 0..127
    const int blk = (tid & 1) * 8;   // 0,8

    for (int k0 = 0; k0 < EE; k0 += 16) {
        float4 av = *(const float4*)(A + (size_t)(m0 + alr) * EE + k0 + alk);
        As[alk + 0][alr] = av.x;
        As[alk + 1][alr] = av.y;
        As[alk + 2][alr] = av.z;
        As[alk + 3][alr] = av.w;
        const float* wp = W + (size_t)(n0 + blr) * EE + k0 + blk;
        float4 w0 = *(const float4*)(wp);
        float4 w1 = *(const float4*)(wp + 4);
        Bs[blk + 0][blr] = w0.x;
        Bs[blk + 1][blr] = w0.y;
        Bs[blk + 2][blr] = w0.z;
        Bs[blk + 3][blr] = w0.w;
        Bs[blk + 4][blr] = w1.x;
        Bs[blk + 5][blr] = w1.y;
        Bs[blk + 6][blr] = w1.z;
        Bs[blk + 7][blr] = w1.w;
        __syncthreads();
        #pragma unroll
        for (int kk = 0; kk < 16; kk++) {
            float a[4], b[8];
            *(float4*)a     = *(const float4*)&As[kk][my * 4];
            *(float4*)&b[0] = *(const float4*)&Bs[kk][nx * 8];
            *(float4*)&b[4] = *(const float4*)&Bs[kk][nx * 8 + 4];
            #pragma unroll
            for (int i = 0; i < 4; i++)
                #pragma unroll
                for (int j = 0; j < 8; j++)
                    acc[i][j] += a[i] * b[j];
        }
        __syncthreads();
    }
    #pragma unroll
    for (int i = 0; i < 4; i++) {
        int m = m0 + my * 4 + i;
        #pragma unroll
        for (int j = 0; j < 8; j++) {
            int n = n0 + nx * 8 + j;
            float v = acc[i][j];
            if (bias) v += bias[n];
            if (relu) v = fmaxf(v, 0.0f);
            size_t idx;
            if (qlayout) {   // q[b,h,t,d]
                int b = m >> 11, t = m & 2047, h = n >> 6, d = n & 63;
                idx = ((size_t)(b * HH + h) * TT + t) * DD + d;
            } else {
                idx = (size_t)m * EE + n;
            }
            Cout[idx] = v;
        }
    }
}

// ---------------- flash attention (q = k = v), causal + exact-zero quirk ----------------
#define APAD 68
__global__ __launch_bounds__(256) void k_attn(const float* __restrict__ q,
                                              float* __restrict__ cat)
{
    __shared__ float Qs[64][APAD];
    __shared__ float Ks[64][APAD];
    __shared__ float Ps[64][APAD];
    const int tile = blockIdx.x;       // 0..31 (query tile)
    const int bh = blockIdx.y;         // 0..23
    const int bb = bh / HH, hh = bh % HH;
    const float* qb = q + (size_t)bh * TT * DD;
    const int m0 = tile * 64;
    const int tid = threadIdx.x;
    const int r = tid >> 3;            // 0..31 ; handles rows r, r+32
    const int c8 = tid & 7;
    const int d0 = c8 * 8;

    const int qr = tid >> 2;           // loader: row 0..63
    const int qd = (tid & 3) * 16;     // 0,16,32,48
    {
        const float* qp = qb + (size_t)(m0 + qr) * DD + qd;
        *(float4*)&Qs[qr][qd + 0]  = *(const float4*)(qp + 0);
        *(float4*)&Qs[qr][qd + 4]  = *(const float4*)(qp + 4);
        *(float4*)&Qs[qr][qd + 8]  = *(const float4*)(qp + 8);
        *(float4*)&Qs[qr][qd + 12] = *(const float4*)(qp + 12);
    }

    float accO[2][8];
    #pragma unroll
    for (int rr = 0; rr < 2; rr++)
        #pragma unroll
        for (int dd = 0; dd < 8; dd++) accO[rr][dd] = 0.0f;
    float mi[2] = {-INFINITY, -INFINITY};
    float li[2] = {0.0f, 0.0f};
    const int ta = m0 + r, tb = m0 + r + 32;

    for (int kt = 0; kt <= tile; kt++) {
        const int s0 = kt * 64;
        __syncthreads();   // prev iter's reads of Ks done; Qs store visible (1st iter)
        {
            const float* kp = qb + (size_t)(s0 + qr) * DD + qd;
            *(float4*)&Ks[qr][qd + 0]  = *(const float4*)(kp + 0);
            *(float4*)&Ks[qr][qd + 4]  = *(const float4*)(kp + 4);
            *(float4*)&Ks[qr][qd + 8]  = *(const float4*)(kp + 8);
            *(float4*)&Ks[qr][qd + 12] = *(const float4*)(kp + 12);
        }
        __syncthreads();

        // ---- scores: 2 rows x 8 keys per thread (keys j = c8 + 8*jj) ----
        float sc[2][8];
        #pragma unroll
        for (int rr = 0; rr < 2; rr++)
            #pragma unroll
            for (int jj = 0; jj < 8; jj++) sc[rr][jj] = 0.0f;
        #pragma unroll 4
        for (int d = 0; d < 64; d += 4) {
            float qa[4], qbv[4];
            *(float4*)qa  = *(const float4*)&Qs[r][d];
            *(float4*)qbv = *(const float4*)&Qs[r + 32][d];
            #pragma unroll
            for (int jj = 0; jj < 8; jj++) {
                float kv[4];
                *(float4*)kv = *(const float4*)&Ks[c8 + 8 * jj][d];
                sc[0][jj] += qa[0]*kv[0] + qa[1]*kv[1] + qa[2]*kv[2] + qa[3]*kv[3];
                sc[1][jj] += qbv[0]*kv[0] + qbv[1]*kv[1] + qbv[2]*kv[2] + qbv[3]*kv[3];
            }
        }

        // ---- mask (scale -> tril-zero -> zero==-inf quirk), tile max ----
        float mx[2] = {-INFINITY, -INFINITY};
        #pragma unroll
        for (int jj = 0; jj < 8; jj++) {
            int jg = s0 + c8 + 8 * jj;
            #pragma unroll
            for (int rr = 0; rr < 2; rr++) {
                int tg = (rr == 0) ? ta : tb;
                float v = sc[rr][jj] * 0.125f;
                v = (jg <= tg) ? v : 0.0f;
                v = (v == 0.0f) ? -INFINITY : v;
                sc[rr][jj] = v;
                mx[rr] = fmaxf(mx[rr], v);
            }
        }
        #pragma unroll
        for (int o = 1; o < 8; o <<= 1) {
            mx[0] = fmaxf(mx[0], __shfl_xor(mx[0], o, 64));
            mx[1] = fmaxf(mx[1], __shfl_xor(mx[1], o, 64));
        }

        // ---- online softmax update ----
        #pragma unroll
        for (int rr = 0; rr < 2; rr++) {
            int row = r + rr * 32;
            float mnew = fmaxf(mi[rr], mx[rr]);
            float alpha = (mnew == -INFINITY) ? 1.0f : __expf(mi[rr] - mnew);
            float lsum = 0.0f;
            #pragma unroll
            for (int jj = 0; jj < 8; jj++) {
                float v = sc[rr][jj];
                float p = (v == -INFINITY) ? 0.0f : __expf(v - mnew);
                lsum += p;
                Ps[row][c8 + 8 * jj] = p;
            }
            #pragma unroll
            for (int o = 1; o < 8; o <<= 1) lsum += __shfl_xor(lsum, o, 64);
            li[rr] = li[rr] * alpha + lsum;
            mi[rr] = mnew;
            #pragma unroll
            for (int dd = 0; dd < 8; dd++) accO[rr][dd] *= alpha;
        }
        __syncthreads();   // Ps visible to the whole block

        // ---- O += P @ V (V = K tile) ----
        #pragma unroll 4
        for (int j4 = 0; j4 < 64; j4 += 4) {
            float pa[4], pb[4];
            *(float4*)pa = *(const float4*)&Ps[r][j4];
            *(float4*)pb = *(const float4*)&Ps[r + 32][j4];
            #pragma unroll
            for (int u = 0; u < 4; u++) {
                float kv[8];
                *(float4*)&kv[0] = *(const float4*)&Ks[j4 + u][d0];
                *(float4*)&kv[4] = *(const float4*)&Ks[j4 + u][d0 + 4];
                #pragma unroll
                for (int dd = 0; dd < 8; dd++) {
                    accO[0][dd] += pa[u] * kv[dd];
                    accO[1][dd] += pb[u] * kv[dd];
                }
            }
        }
    }

    // ---- normalize + write concat layout [B,T,E] ----
    #pragma unroll
    for (int rr = 0; rr < 2; rr++) {
        int row = r + rr * 32;
        int t = m0 + row;
        float inv = 1.0f / li[rr];
        float* op = cat + ((size_t)bb * TT + t) * EE + hh * DD + d0;
        #pragma unroll
        for (int dd = 0; dd < 8; dd++) op[dd] = accO[rr][dd] * inv;
    }
}

// ---------------- LayerNorm: out = LN(x + pre) (all fp32) ----------------
__global__ __launch_bounds__(256) void k_ln(const float* __restrict__ x,
                                            const float* __restrict__ pre,
                                            const float* __restrict__ g,
                                            const float* __restrict__ be,
                                            float* __restrict__ out)
{
    const int w = threadIdx.x >> 6, l = threadIdx.x & 63;
    const int m = blockIdx.x * 4 + w;
    const float* xp = x + (size_t)m * EE;
    const float* pp = pre + (size_t)m * EE;
    float v[6], s = 0.0f, s2 = 0.0f;
    #pragma unroll
    for (int i = 0; i < 6; i++) {
        int e = l + 64 * i;
        float a = xp[e] + pp[e];
        v[i] = a; s += a; s2 += a * a;
    }
    #pragma unroll
    for (int o = 1; o < 64; o <<= 1) { s += __shfl_xor(s, o, 64); s2 += __shfl_xor(s2, o, 64); }
    float mu = s * (1.0f / EE);
    float var = s2 * (1.0f / EE) - mu * mu;
    float rs = rsqrtf(var + 1e-5f);
    float* op = out + (size_t)m * EE;
    #pragma unroll
    for (int i = 0; i < 6; i++) {
        int e = l + 64 * i;
        op[e] = (v[i] - mu) * rs * g[e] + be[e];
    }
}

extern "C" void kernel_launch(void* const* d_in, const int* in_sizes, int n_in,
                              void* d_out, int out_size, void* d_ws, size_t ws_size,
                              hipStream_t stream) {
    (void)in_sizes; (void)n_in; (void)out_size; (void)ws_size;
    const float* x   = (const float*)d_in[0];
    const float* Wq  = (const float*)d_in[1];
    const float* Wo  = (const float*)d_in[2];
    const float* bo  = (const float*)d_in[3];
    const float* W1  = (const float*)d_in[4];
    const float* b1  = (const float*)d_in[5];
    const float* W2  = (const float*)d_in[6];
    const float* b2  = (const float*)d_in[7];
    const float* g1  = (const float*)d_in[8];
    const float* be1 = (const float*)d_in[9];
    const float* g2  = (const float*)d_in[10];
    const float* be2 = (const float*)d_in[11];
    float* out = (float*)d_out;

    float* ws = (float*)d_ws;
    const size_t SZ = (size_t)MM * EE;    // 3,145,728 floats
    float* S0 = ws;            // sa (pre-residual proj out)
    float* S1 = ws + SZ;       // q, later x1 (post-LN1)
    float* S2 = ws + 2 * SZ;   // cat, later ffn-out (pre-residual)
    float* H1 = out;           // ffn hidden reuses d_out (consumed before final write)

    k_gemm<<<dim3(MM / 64, EE / 128), dim3(256), 0, stream>>>(x, Wq, nullptr, S1, 0, 1);
    k_attn<<<dim3(TT / 64, BB * HH), dim3(256), 0, stream>>>(S1, S2);
    k_gemm<<<dim3(MM / 64, EE / 128), dim3(256), 0, stream>>>(S2, Wo, bo, S0, 0, 0);
    k_ln<<<dim3(MM / 4), dim3(256), 0, stream>>>(x, S0, g1, be1, S1);
    k_gemm<<<dim3(MM / 64, EE / 128), dim3(256), 0, stream>>>(S1, W1, b1, H1, 1, 0);
    k_gemm<<<dim3(MM / 64, EE / 128), dim3(256), 0, stream>>>(H1, W2, b2, S2, 0, 0);
    k_ln<<<dim3(MM / 4), dim3(256), 0, stream>>>(S1, S2, g2, be2, out);
}

// Round 3
// 395.788 us; speedup vs baseline: 1.7902x; 1.7902x over previous
//
#include <hip/hip_runtime.h>
#include <math.h>

#define BB 4
#define TT 2048
#define EE 384
#define HH 6
#define DD 64
#define MM (BB*TT)   // 8192 tokens

typedef __attribute__((ext_vector_type(8))) short bf16x8;
typedef __attribute__((ext_vector_type(4))) float f32x4;

__device__ __forceinline__ unsigned short f2bf(float f) {
    unsigned int u = __float_as_uint(f);
    u = (u + 0x7FFFu + ((u >> 16) & 1u)) >> 16;   // RNE
    return (unsigned short)u;
}

// ---------------- tiled GEMM: C[m,n] = A[m,:] . W[n,:] (+bias, relu) ----------------
// A fp32 [M,384], W fp32 [N,384]. Tile 64(m) x 128(n), BK=16, 256 thr, 4x8 micro.
// qlayout: write bf16 q[b,h,t,d] instead of fp32 row-major.
__global__ __launch_bounds__(256) void k_gemm(const float* __restrict__ A,
                                              const float* __restrict__ W,
                                              const float* __restrict__ bias,
                                              float* __restrict__ Cout,
                                              int relu, int qlayout)
{
    __shared__ float As[16][68];     // [k][m]
    __shared__ float Bs[16][136];    // [k][n]
    const int m0 = blockIdx.x * 64;
    const int n0 = blockIdx.y * 128;
    const int tid = threadIdx.x;
    const int my = tid & 15;
    const int nx = tid >> 4;
    float acc[4][8];
    #pragma unroll
    for (int i = 0; i < 4; i++)
        #pragma unroll
        for (int j = 0; j < 8; j++) acc[i][j] = 0.0f;

    const int alr = tid >> 2;
    const int alk = (tid & 3) * 4;
    const int blr = tid >> 1;
    const int blk = (tid & 1) * 8;

    for (int k0 = 0; k0 < EE; k0 += 16) {
        float4 av = *(const float4*)(A + (size_t)(m0 + alr) * EE + k0 + alk);
        As[alk + 0][alr] = av.x;
        As[alk + 1][alr] = av.y;
        As[alk + 2][alr] = av.z;
        As[alk + 3][alr] = av.w;
        const float* wp = W + (size_t)(n0 + blr) * EE + k0 + blk;
        float4 w0 = *(const float4*)(wp);
        float4 w1 = *(const float4*)(wp + 4);
        Bs[blk + 0][blr] = w0.x;
        Bs[blk + 1][blr] = w0.y;
        Bs[blk + 2][blr] = w0.z;
        Bs[blk + 3][blr] = w0.w;
        Bs[blk + 4][blr] = w1.x;
        Bs[blk + 5][blr] = w1.y;
        Bs[blk + 6][blr] = w1.z;
        Bs[blk + 7][blr] = w1.w;
        __syncthreads();
        #pragma unroll
        for (int kk = 0; kk < 16; kk++) {
            float a[4], b[8];
            *(float4*)a     = *(const float4*)&As[kk][my * 4];
            *(float4*)&b[0] = *(const float4*)&Bs[kk][nx * 8];
            *(float4*)&b[4] = *(const float4*)&Bs[kk][nx * 8 + 4];
            #pragma unroll
            for (int i = 0; i < 4; i++)
                #pragma unroll
                for (int j = 0; j < 8; j++)
                    acc[i][j] += a[i] * b[j];
        }
        __syncthreads();
    }
    #pragma unroll
    for (int i = 0; i < 4; i++) {
        int m = m0 + my * 4 + i;
        #pragma unroll
        for (int j = 0; j < 8; j++) {
            int n = n0 + nx * 8 + j;
            float v = acc[i][j];
            if (bias) v += bias[n];
            if (relu) v = fmaxf(v, 0.0f);
            if (qlayout) {   // q[b,h,t,d] bf16
                int b = m >> 11, t = m & 2047, h = n >> 6, d = n & 63;
                size_t idx = ((size_t)(b * HH + h) * TT + t) * DD + d;
                ((unsigned short*)Cout)[idx] = f2bf(v);
            } else {
                Cout[(size_t)m * EE + n] = v;
            }
        }
    }
}

// ---------------- transpose qbf[b,h,t,d] -> qbfT[b,h,d,t] (bf16) ----------------
__global__ __launch_bounds__(256) void k_prep(const unsigned short* __restrict__ qbf,
                                              unsigned short* __restrict__ qbfT)
{
    __shared__ unsigned short Ls[64][72];
    const int bh = blockIdx.y;
    const int t0 = blockIdx.x * 64;
    const unsigned short* src = qbf + ((size_t)bh * TT + t0) * DD;
    {
        int r = threadIdx.x >> 2, c = (threadIdx.x & 3) * 16;
        const unsigned short* p = src + (size_t)r * DD + c;
        *(uint4*)&Ls[r][c]     = *(const uint4*)(p);
        *(uint4*)&Ls[r][c + 8] = *(const uint4*)(p + 8);
    }
    __syncthreads();
    {
        int d = threadIdx.x >> 2, tc = (threadIdx.x & 3) * 16;
        unsigned short tmp[16];
        #pragma unroll
        for (int i = 0; i < 16; i++) tmp[i] = Ls[tc + i][d];
        unsigned short* dst = qbfT + ((size_t)bh * DD + d) * TT + t0 + tc;
        *(uint4*)(dst)     = *(const uint4*)&tmp[0];
        *(uint4*)(dst + 8) = *(const uint4*)&tmp[8];
    }
}

// ---------------- MFMA flash attention (q = k = v), causal + exact-zero quirk ----------
__global__ __launch_bounds__(256, 4) void k_attn(const unsigned short* __restrict__ qbf,
                                                 const unsigned short* __restrict__ qbfT,
                                                 float* __restrict__ cat)
{
    __shared__ unsigned short Qs[64][72];   // [q][d]
    __shared__ unsigned short Ks[64][72];   // [key][d]  (B-operand for QK^T)
    __shared__ unsigned short Vs[64][72];   // [d][key]  (B-operand for PV)
    __shared__ unsigned short Ps[64][72];   // [q][key]  (A-operand for PV, wave-private rows)
    const int tile = blockIdx.x;            // query tile 0..31
    const int bh = blockIdx.y;              // 0..23
    const int bb = bh / HH, hh = bh % HH;
    const int m0 = tile * 64;
    const int tid = threadIdx.x;
    const int w = tid >> 6, lane = tid & 63;
    const int fr = lane & 15;               // fragment row/col index
    const int fc = (lane >> 4) * 8;         // fragment k-offset (quad*8)
    const unsigned short* qb  = qbf  + (size_t)bh * TT * DD;
    const unsigned short* qtb = qbfT + (size_t)bh * DD * TT;

    // ---- stage Q tile (once) ----
    {
        int r = tid >> 2, c = (tid & 3) * 16;
        const unsigned short* p = qb + (size_t)(m0 + r) * DD + c;
        *(uint4*)&Qs[r][c]     = *(const uint4*)(p);
        *(uint4*)&Qs[r][c + 8] = *(const uint4*)(p + 8);
    }
    __syncthreads();
    const bf16x8 qA0 = *(const bf16x8*)&Qs[w * 16 + fr][fc];
    const bf16x8 qA1 = *(const bf16x8*)&Qs[w * 16 + fr][fc + 32];

    f32x4 accO[4];                 // [d-tile][row-reg]
    #pragma unroll
    for (int dt = 0; dt < 4; dt++) accO[dt] = (f32x4){0.f, 0.f, 0.f, 0.f};
    float mi[4], li[4];
    #pragma unroll
    for (int r = 0; r < 4; r++) { mi[r] = -INFINITY; li[r] = 0.0f; }
    const int rowbase = m0 + w * 16 + (lane >> 4) * 4;   // + reg = global t

    for (int kt = 0; kt <= tile; kt++) {
        const int s0 = kt * 64;
        __syncthreads();           // previous iter's frag reads of Ks/Vs done
        {
            int r = tid >> 2, c = (tid & 3) * 16;
            const unsigned short* kp = qb + (size_t)(s0 + r) * DD + c;
            *(uint4*)&Ks[r][c]     = *(const uint4*)(kp);
            *(uint4*)&Ks[r][c + 8] = *(const uint4*)(kp + 8);
            const unsigned short* vp = qtb + (size_t)r * TT + s0 + c;
            *(uint4*)&Vs[r][c]     = *(const uint4*)(vp);
            *(uint4*)&Vs[r][c + 8] = *(const uint4*)(vp + 8);
        }
        __syncthreads();

        // ---- S = Q . K^T : four 16x16 n-tiles, K=64 in two MFMA steps ----
        f32x4 S[4];
        #pragma unroll
        for (int nt = 0; nt < 4; nt++) {
            f32x4 acc = (f32x4){0.f, 0.f, 0.f, 0.f};
            bf16x8 b0 = *(const bf16x8*)&Ks[nt * 16 + fr][fc];
            acc = __builtin_amdgcn_mfma_f32_16x16x32_bf16(qA0, b0, acc, 0, 0, 0);
            bf16x8 b1 = *(const bf16x8*)&Ks[nt * 16 + fr][fc + 32];
            acc = __builtin_amdgcn_mfma_f32_16x16x32_bf16(qA1, b1, acc, 0, 0, 0);
            S[nt] = acc;
        }

        // ---- mask (scale -> tril-zero -> zero==-inf quirk) + row max ----
        float mx[4] = {-INFINITY, -INFINITY, -INFINITY, -INFINITY};
        #pragma unroll
        for (int nt = 0; nt < 4; nt++) {
            int jg = s0 + nt * 16 + fr;
            #pragma unroll
            for (int r = 0; r < 4; r++) {
                float v = S[nt][r] * 0.125f;
                v = (jg <= rowbase + r) ? v : 0.0f;
                v = (v == 0.0f) ? -INFINITY : v;
                S[nt][r] = v;
                mx[r] = fmaxf(mx[r], v);
            }
        }
        #pragma unroll
        for (int r = 0; r < 4; r++) {
            #pragma unroll
            for (int o = 1; o < 16; o <<= 1) mx[r] = fmaxf(mx[r], __shfl_xor(mx[r], o, 64));
        }

        // ---- online softmax: rescale, exp, write P (bf16, wave-private rows) ----
        float al[4], ls[4];
        #pragma unroll
        for (int r = 0; r < 4; r++) {
            float mnew = fmaxf(mi[r], mx[r]);
            al[r] = (mnew == -INFINITY) ? 1.0f : __expf(mi[r] - mnew);
            mi[r] = mnew;
            ls[r] = 0.0f;
        }
        #pragma unroll
        for (int nt = 0; nt < 4; nt++) {
            #pragma unroll
            for (int r = 0; r < 4; r++) {
                float v = S[nt][r];
                float p = (v == -INFINITY) ? 0.0f : __expf(v - mi[r]);
                ls[r] += p;
                Ps[w * 16 + (lane >> 4) * 4 + r][nt * 16 + fr] = f2bf(p);
            }
        }
        #pragma unroll
        for (int r = 0; r < 4; r++) {
            #pragma unroll
            for (int o = 1; o < 16; o <<= 1) ls[r] += __shfl_xor(ls[r], o, 64);
            li[r] = li[r] * al[r] + ls[r];
        }
        #pragma unroll
        for (int dt = 0; dt < 4; dt++)
            #pragma unroll
            for (int r = 0; r < 4; r++) accO[dt][r] *= al[r];

        // ---- O += P . V : A-frags from Ps (same wave wrote them), B from Vs ----
        bf16x8 pA0 = *(const bf16x8*)&Ps[w * 16 + fr][fc];
        bf16x8 pA1 = *(const bf16x8*)&Ps[w * 16 + fr][fc + 32];
        #pragma unroll
        for (int dt = 0; dt < 4; dt++) {
            bf16x8 v0 = *(const bf16x8*)&Vs[dt * 16 + fr][fc];
            accO[dt] = __builtin_amdgcn_mfma_f32_16x16x32_bf16(pA0, v0, accO[dt], 0, 0, 0);
            bf16x8 v1 = *(const bf16x8*)&Vs[dt * 16 + fr][fc + 32];
            accO[dt] = __builtin_amdgcn_mfma_f32_16x16x32_bf16(pA1, v1, accO[dt], 0, 0, 0);
        }
    }

    // ---- normalize + write concat layout [B,T,E] fp32 ----
    float inv[4];
    #pragma unroll
    for (int r = 0; r < 4; r++) inv[r] = 1.0f / li[r];
    #pragma unroll
    for (int dt = 0; dt < 4; dt++) {
        #pragma unroll
        for (int r = 0; r < 4; r++) {
            int t = rowbase + r;
            cat[((size_t)bb * TT + t) * EE + hh * DD + dt * 16 + fr] = accO[dt][r] * inv[r];
        }
    }
}

// ---------------- LayerNorm: out = LN(x + pre) (all fp32) ----------------
__global__ __launch_bounds__(256) void k_ln(const float* __restrict__ x,
                                            const float* __restrict__ pre,
                                            const float* __restrict__ g,
                                            const float* __restrict__ be,
                                            float* __restrict__ out)
{
    const int w = threadIdx.x >> 6, l = threadIdx.x & 63;
    const int m = blockIdx.x * 4 + w;
    const float* xp = x + (size_t)m * EE;
    const float* pp = pre + (size_t)m * EE;
    float v[6], s = 0.0f, s2 = 0.0f;
    #pragma unroll
    for (int i = 0; i < 6; i++) {
        int e = l + 64 * i;
        float a = xp[e] + pp[e];
        v[i] = a; s += a; s2 += a * a;
    }
    #pragma unroll
    for (int o = 1; o < 64; o <<= 1) { s += __shfl_xor(s, o, 64); s2 += __shfl_xor(s2, o, 64); }
    float mu = s * (1.0f / EE);
    float var = s2 * (1.0f / EE) - mu * mu;
    float rs = rsqrtf(var + 1e-5f);
    float* op = out + (size_t)m * EE;
    #pragma unroll
    for (int i = 0; i < 6; i++) {
        int e = l + 64 * i;
        op[e] = (v[i] - mu) * rs * g[e] + be[e];
    }
}

extern "C" void kernel_launch(void* const* d_in, const int* in_sizes, int n_in,
                              void* d_out, int out_size, void* d_ws, size_t ws_size,
                              hipStream_t stream) {
    (void)in_sizes; (void)n_in; (void)out_size; (void)ws_size;
    const float* x   = (const float*)d_in[0];
    const float* Wq  = (const float*)d_in[1];
    const float* Wo  = (const float*)d_in[2];
    const float* bo  = (const float*)d_in[3];
    const float* W1  = (const float*)d_in[4];
    const float* b1  = (const float*)d_in[5];
    const float* W2  = (const float*)d_in[6];
    const float* b2  = (const float*)d_in[7];
    const float* g1  = (const float*)d_in[8];
    const float* be1 = (const float*)d_in[9];
    const float* g2  = (const float*)d_in[10];
    const float* be2 = (const float*)d_in[11];
    float* out = (float*)d_out;

    float* ws = (float*)d_ws;
    const size_t SZ = (size_t)MM * EE;    // 3,145,728 floats
    float* S0 = ws;            // sa (pre-residual proj out)
    float* S1 = ws + SZ;       // qbf+qbfT (bf16), later x1 (post-LN1 fp32)
    float* S2 = ws + 2 * SZ;   // cat, later ffn-out
    float* H1 = out;           // ffn hidden reuses d_out

    unsigned short* qbf  = (unsigned short*)S1;
    unsigned short* qbfT = qbf + (size_t)MM * DD * HH / HH * 1;  // see below
    qbfT = qbf + (size_t)BB * HH * TT * DD;                      // 3,145,728 ushorts

    k_gemm<<<dim3(MM / 64, EE / 128), dim3(256), 0, stream>>>(x, Wq, nullptr, (float*)qbf, 0, 1);
    k_prep<<<dim3(TT / 64, BB * HH), dim3(256), 0, stream>>>(qbf, qbfT);
    k_attn<<<dim3(TT / 64, BB * HH), dim3(256), 0, stream>>>(qbf, qbfT, S2);
    k_gemm<<<dim3(MM / 64, EE / 128), dim3(256), 0, stream>>>(S2, Wo, bo, S0, 0, 0);
    k_ln<<<dim3(MM / 4), dim3(256), 0, stream>>>(x, S0, g1, be1, S1);
    k_gemm<<<dim3(MM / 64, EE / 128), dim3(256), 0, stream>>>(S1, W1, b1, H1, 1, 0);
    k_gemm<<<dim3(MM / 64, EE / 128), dim3(256), 0, stream>>>(H1, W2, b2, S2, 0, 0);
    k_ln<<<dim3(MM / 4), dim3(256), 0, stream>>>(S1, S2, g2, be2, out);
}

// Round 4
// 299.710 us; speedup vs baseline: 2.3641x; 1.3206x over previous
//
#include <hip/hip_runtime.h>
#include <math.h>

#define BB 4
#define TT 2048
#define EE 384
#define HH 6
#define DD 64
#define MM (BB*TT)   // 8192 tokens

typedef __attribute__((ext_vector_type(8))) short bf16x8;
typedef __attribute__((ext_vector_type(4))) float f32x4;

__device__ __forceinline__ unsigned short f2bf(float f) {
    unsigned int u = __float_as_uint(f);
    u = (u + 0x7FFFu + ((u >> 16) & 1u)) >> 16;   // RNE
    return (unsigned short)u;
}
__device__ __forceinline__ unsigned int pk2(float a, float b) {
    return (unsigned int)f2bf(a) | ((unsigned int)f2bf(b) << 16);
}

// ---------------- fp32 -> bf16 conversion: x (3072 blocks) + 4 weights (144 each) -----
__global__ __launch_bounds__(256) void k_cvt(const float* __restrict__ x,
                                             const float* __restrict__ wq,
                                             const float* __restrict__ wo,
                                             const float* __restrict__ w1,
                                             const float* __restrict__ w2,
                                             unsigned short* __restrict__ xb,
                                             unsigned short* __restrict__ wqb,
                                             unsigned short* __restrict__ wob,
                                             unsigned short* __restrict__ w1b,
                                             unsigned short* __restrict__ w2b)
{
    int bid = blockIdx.x;
    const float* src; unsigned short* dst; int i;
    if (bid < 3072)       { src = x;  dst = xb;  i = bid * 256; }
    else {
        int r = bid - 3072, wi = r / 144, off = (r % 144) * 256;
        const float* s4[4] = {wq, wo, w1, w2};
        unsigned short* d4[4] = {wqb, wob, w1b, w2b};
        src = s4[wi]; dst = d4[wi]; i = off;
    }
    i += threadIdx.x;
    float4 v = ((const float4*)src)[i];
    uint2 o; o.x = pk2(v.x, v.y); o.y = pk2(v.z, v.w);
    ((uint2*)dst)[i] = o;
}

// ---------------- MFMA GEMM: C[m,n] = A[m,:].W[n,:] (+bias, relu), bf16 in fp32 acc ---
// A bf16 [M,384], W bf16 [N,384]. Block 32m x 192n, 4 waves (16m x 96n each), no LDS.
// flags: 1=relu, 2=bf16 out, 4=qlayout (bf16 q[b,h,t,d])
__global__ __launch_bounds__(256, 2) void k_mgemm(const unsigned short* __restrict__ A,
                                                  const unsigned short* __restrict__ W,
                                                  const float* __restrict__ bias,
                                                  void* __restrict__ Cout, int flags)
{
    const int tid = threadIdx.x;
    const int w = tid >> 6, lane = tid & 63;
    const int fr = lane & 15, quad = lane >> 4;
    const int m0 = blockIdx.x * 32 + (w & 1) * 16;
    const int n0 = blockIdx.y * 192 + (w >> 1) * 96;
    const unsigned short* Ap = A + (size_t)(m0 + fr) * EE + quad * 8;
    const unsigned short* Wp = W + (size_t)(n0 + fr) * EE + quad * 8;

    f32x4 acc[6];
    #pragma unroll
    for (int nt = 0; nt < 6; nt++) acc[nt] = (f32x4){0.f, 0.f, 0.f, 0.f};

    #pragma unroll
    for (int k0 = 0; k0 < 12; k0++) {
        bf16x8 a = *(const bf16x8*)(Ap + k0 * 32);
        #pragma unroll
        for (int nt = 0; nt < 6; nt++) {
            bf16x8 b = *(const bf16x8*)(Wp + (size_t)nt * 16 * EE + k0 * 32);
            acc[nt] = __builtin_amdgcn_mfma_f32_16x16x32_bf16(a, b, acc[nt], 0, 0, 0);
        }
    }

    const int mrow = m0 + quad * 4;
    #pragma unroll
    for (int nt = 0; nt < 6; nt++) {
        int n = n0 + nt * 16 + fr;
        float bv = bias ? bias[n] : 0.0f;
        #pragma unroll
        for (int r = 0; r < 4; r++) {
            int m = mrow + r;
            float v = acc[nt][r] + bv;
            if (flags & 1) v = fmaxf(v, 0.0f);
            if (flags & 4) {          // q[b,h,t,d] bf16
                int b = m >> 11, t = m & 2047, h = n >> 6, d = n & 63;
                ((unsigned short*)Cout)[((size_t)(b * HH + h) * TT + t) * DD + d] = f2bf(v);
            } else if (flags & 2) {   // bf16 row-major
                ((unsigned short*)Cout)[(size_t)m * EE + n] = f2bf(v);
            } else {                  // fp32 row-major
                ((float*)Cout)[(size_t)m * EE + n] = v;
            }
        }
    }
}

// ---------------- transpose qbf[b,h,t,d] -> qbfT[b,h,d,t] (bf16) ----------------
__global__ __launch_bounds__(256) void k_prep(const unsigned short* __restrict__ qbf,
                                              unsigned short* __restrict__ qbfT)
{
    __shared__ unsigned short Ls[64][72];
    const int bh = blockIdx.y;
    const int t0 = blockIdx.x * 64;
    const unsigned short* src = qbf + ((size_t)bh * TT + t0) * DD;
    {
        int r = threadIdx.x >> 2, c = (threadIdx.x & 3) * 16;
        const unsigned short* p = src + (size_t)r * DD + c;
        *(uint4*)&Ls[r][c]     = *(const uint4*)(p);
        *(uint4*)&Ls[r][c + 8] = *(const uint4*)(p + 8);
    }
    __syncthreads();
    {
        int d = threadIdx.x >> 2, tc = (threadIdx.x & 3) * 16;
        unsigned short tmp[16];
        #pragma unroll
        for (int i = 0; i < 16; i++) tmp[i] = Ls[tc + i][d];
        unsigned short* dst = qbfT + ((size_t)bh * DD + d) * TT + t0 + tc;
        *(uint4*)(dst)     = *(const uint4*)&tmp[0];
        *(uint4*)(dst + 8) = *(const uint4*)&tmp[8];
    }
}

// ---------------- MFMA flash attention (q = k = v), causal + exact-zero quirk ----------
__global__ __launch_bounds__(256, 4) void k_attn(const unsigned short* __restrict__ qbf,
                                                 const unsigned short* __restrict__ qbfT,
                                                 unsigned short* __restrict__ cat)
{
    __shared__ unsigned short Qs[64][72];   // [q][d]
    __shared__ unsigned short Ks[64][72];   // [key][d]
    __shared__ unsigned short Vs[64][72];   // [d][key]
    __shared__ unsigned short Ps[64][72];   // [q][key]
    const int tile = blockIdx.x;
    const int bh = blockIdx.y;
    const int bb = bh / HH, hh = bh % HH;
    const int m0 = tile * 64;
    const int tid = threadIdx.x;
    const int w = tid >> 6, lane = tid & 63;
    const int fr = lane & 15;
    const int fc = (lane >> 4) * 8;
    const unsigned short* qb  = qbf  + (size_t)bh * TT * DD;
    const unsigned short* qtb = qbfT + (size_t)bh * DD * TT;

    {
        int r = tid >> 2, c = (tid & 3) * 16;
        const unsigned short* p = qb + (size_t)(m0 + r) * DD + c;
        *(uint4*)&Qs[r][c]     = *(const uint4*)(p);
        *(uint4*)&Qs[r][c + 8] = *(const uint4*)(p + 8);
    }
    __syncthreads();
    const bf16x8 qA0 = *(const bf16x8*)&Qs[w * 16 + fr][fc];
    const bf16x8 qA1 = *(const bf16x8*)&Qs[w * 16 + fr][fc + 32];

    f32x4 accO[4];
    #pragma unroll
    for (int dt = 0; dt < 4; dt++) accO[dt] = (f32x4){0.f, 0.f, 0.f, 0.f};
    float mi[4], li[4];
    #pragma unroll
    for (int r = 0; r < 4; r++) { mi[r] = -INFINITY; li[r] = 0.0f; }
    const int rowbase = m0 + w * 16 + (lane >> 4) * 4;

    for (int kt = 0; kt <= tile; kt++) {
        const int s0 = kt * 64;
        __syncthreads();
        {
            int r = tid >> 2, c = (tid & 3) * 16;
            const unsigned short* kp = qb + (size_t)(s0 + r) * DD + c;
            *(uint4*)&Ks[r][c]     = *(const uint4*)(kp);
            *(uint4*)&Ks[r][c + 8] = *(const uint4*)(kp + 8);
            const unsigned short* vp = qtb + (size_t)r * TT + s0 + c;
            *(uint4*)&Vs[r][c]     = *(const uint4*)(vp);
            *(uint4*)&Vs[r][c + 8] = *(const uint4*)(vp + 8);
        }
        __syncthreads();

        f32x4 S[4];
        #pragma unroll
        for (int nt = 0; nt < 4; nt++) {
            f32x4 acc = (f32x4){0.f, 0.f, 0.f, 0.f};
            bf16x8 b0 = *(const bf16x8*)&Ks[nt * 16 + fr][fc];
            acc = __builtin_amdgcn_mfma_f32_16x16x32_bf16(qA0, b0, acc, 0, 0, 0);
            bf16x8 b1 = *(const bf16x8*)&Ks[nt * 16 + fr][fc + 32];
            acc = __builtin_amdgcn_mfma_f32_16x16x32_bf16(qA1, b1, acc, 0, 0, 0);
            S[nt] = acc;
        }

        float mx[4] = {-INFINITY, -INFINITY, -INFINITY, -INFINITY};
        #pragma unroll
        for (int nt = 0; nt < 4; nt++) {
            int jg = s0 + nt * 16 + fr;
            #pragma unroll
            for (int r = 0; r < 4; r++) {
                float v = S[nt][r] * 0.125f;
                v = (jg <= rowbase + r) ? v : 0.0f;
                v = (v == 0.0f) ? -INFINITY : v;
                S[nt][r] = v;
                mx[r] = fmaxf(mx[r], v);
            }
        }
        #pragma unroll
        for (int r = 0; r < 4; r++) {
            #pragma unroll
            for (int o = 1; o < 16; o <<= 1) mx[r] = fmaxf(mx[r], __shfl_xor(mx[r], o, 64));
        }

        float al[4], ls[4];
        #pragma unroll
        for (int r = 0; r < 4; r++) {
            float mnew = fmaxf(mi[r], mx[r]);
            al[r] = (mnew == -INFINITY) ? 1.0f : __expf(mi[r] - mnew);
            mi[r] = mnew;
            ls[r] = 0.0f;
        }
        #pragma unroll
        for (int nt = 0; nt < 4; nt++) {
            #pragma unroll
            for (int r = 0; r < 4; r++) {
                float v = S[nt][r];
                float p = (v == -INFINITY) ? 0.0f : __expf(v - mi[r]);
                ls[r] += p;
                Ps[w * 16 + (lane >> 4) * 4 + r][nt * 16 + fr] = f2bf(p);
            }
        }
        #pragma unroll
        for (int r = 0; r < 4; r++) {
            #pragma unroll
            for (int o = 1; o < 16; o <<= 1) ls[r] += __shfl_xor(ls[r], o, 64);
            li[r] = li[r] * al[r] + ls[r];
        }
        #pragma unroll
        for (int dt = 0; dt < 4; dt++)
            #pragma unroll
            for (int r = 0; r < 4; r++) accO[dt][r] *= al[r];

        bf16x8 pA0 = *(const bf16x8*)&Ps[w * 16 + fr][fc];
        bf16x8 pA1 = *(const bf16x8*)&Ps[w * 16 + fr][fc + 32];
        #pragma unroll
        for (int dt = 0; dt < 4; dt++) {
            bf16x8 v0 = *(const bf16x8*)&Vs[dt * 16 + fr][fc];
            accO[dt] = __builtin_amdgcn_mfma_f32_16x16x32_bf16(pA0, v0, accO[dt], 0, 0, 0);
            bf16x8 v1 = *(const bf16x8*)&Vs[dt * 16 + fr][fc + 32];
            accO[dt] = __builtin_amdgcn_mfma_f32_16x16x32_bf16(pA1, v1, accO[dt], 0, 0, 0);
        }
    }

    float inv[4];
    #pragma unroll
    for (int r = 0; r < 4; r++) inv[r] = 1.0f / li[r];
    #pragma unroll
    for (int dt = 0; dt < 4; dt++) {
        #pragma unroll
        for (int r = 0; r < 4; r++) {
            int t = rowbase + r;
            cat[((size_t)bb * TT + t) * EE + hh * DD + dt * 16 + fr] = f2bf(accO[dt][r] * inv[r]);
        }
    }
}

// ---------------- LayerNorm: out = LN(x + pre) fp32 (+ optional bf16 copy) -----------
__global__ __launch_bounds__(256) void k_ln(const float* __restrict__ x,
                                            const float* __restrict__ pre,
                                            const float* __restrict__ g,
                                            const float* __restrict__ be,
                                            float* __restrict__ out,
                                            unsigned short* __restrict__ obf)
{
    const int w = threadIdx.x >> 6, l = threadIdx.x & 63;
    const int m = blockIdx.x * 4 + w;
    const float* xp = x + (size_t)m * EE;
    const float* pp = pre + (size_t)m * EE;
    float v[6], s = 0.0f, s2 = 0.0f;
    #pragma unroll
    for (int i = 0; i < 6; i++) {
        int e = l + 64 * i;
        float a = xp[e] + pp[e];
        v[i] = a; s += a; s2 += a * a;
    }
    #pragma unroll
    for (int o = 1; o < 64; o <<= 1) { s += __shfl_xor(s, o, 64); s2 += __shfl_xor(s2, o, 64); }
    float mu = s * (1.0f / EE);
    float var = s2 * (1.0f / EE) - mu * mu;
    float rs = rsqrtf(var + 1e-5f);
    float* op = out + (size_t)m * EE;
    unsigned short* ob = obf ? obf + (size_t)m * EE : nullptr;
    #pragma unroll
    for (int i = 0; i < 6; i++) {
        int e = l + 64 * i;
        float r = (v[i] - mu) * rs * g[e] + be[e];
        op[e] = r;
        if (ob) ob[e] = f2bf(r);
    }
}

extern "C" void kernel_launch(void* const* d_in, const int* in_sizes, int n_in,
                              void* d_out, int out_size, void* d_ws, size_t ws_size,
                              hipStream_t stream) {
    (void)in_sizes; (void)n_in; (void)out_size; (void)ws_size;
    const float* x   = (const float*)d_in[0];
    const float* Wq  = (const float*)d_in[1];
    const float* Wo  = (const float*)d_in[2];
    const float* bo  = (const float*)d_in[3];
    const float* W1  = (const float*)d_in[4];
    const float* b1  = (const float*)d_in[5];
    const float* W2  = (const float*)d_in[6];
    const float* b2  = (const float*)d_in[7];
    const float* g1  = (const float*)d_in[8];
    const float* be1 = (const float*)d_in[9];
    const float* g2  = (const float*)d_in[10];
    const float* be2 = (const float*)d_in[11];
    float* out = (float*)d_out;

    float* ws = (float*)d_ws;
    const size_t SZ = (size_t)MM * EE;    // 3,145,728 floats / region (12.6 MB)
    float* S0 = ws;                        // sa fp32
    float* S1 = ws + SZ;                   // qbf|qbfT (bf16), later x1 fp32
    float* S2 = ws + 2 * SZ;               // catbf (bf16), later ff fp32
    float* S3 = ws + 3 * SZ;               // xbf / x1bf + weight bf16 copies

    unsigned short* qbf  = (unsigned short*)S1;
    unsigned short* qbfT = qbf + (size_t)MM * DD;          // 3,145,728 ushorts in
    unsigned short* catb = (unsigned short*)S2;
    unsigned short* xbf  = (unsigned short*)S3;            // reused as x1bf later
    unsigned short* wqb  = xbf + SZ;                       // 4 x 147456 ushorts
    unsigned short* wob  = wqb + (size_t)EE * EE;
    unsigned short* w1b  = wob + (size_t)EE * EE;
    unsigned short* w2b  = w1b + (size_t)EE * EE;
    unsigned short* h1b  = (unsigned short*)out;           // ffn hidden bf16 in d_out

    k_cvt<<<dim3(3072 + 4 * 144), dim3(256), 0, stream>>>(x, Wq, Wo, W1, W2,
                                                          xbf, wqb, wob, w1b, w2b);
    k_mgemm<<<dim3(MM / 32, 2), dim3(256), 0, stream>>>(xbf, wqb, nullptr, qbf, 4);
    k_prep<<<dim3(TT / 64, BB * HH), dim3(256), 0, stream>>>(qbf, qbfT);
    k_attn<<<dim3(TT / 64, BB * HH), dim3(256), 0, stream>>>(qbf, qbfT, catb);
    k_mgemm<<<dim3(MM / 32, 2), dim3(256), 0, stream>>>(catb, wob, bo, S0, 0);
    k_ln<<<dim3(MM / 4), dim3(256), 0, stream>>>(x, S0, g1, be1, S1, xbf);
    k_mgemm<<<dim3(MM / 32, 2), dim3(256), 0, stream>>>(xbf, w1b, b1, h1b, 1 | 2);
    k_mgemm<<<dim3(MM / 32, 2), dim3(256), 0, stream>>>(h1b, w2b, b2, S2, 0);
    k_ln<<<dim3(MM / 4), dim3(256), 0, stream>>>(S1, S2, g2, be2, out, nullptr);
}

// Round 6
// 294.509 us; speedup vs baseline: 2.4059x; 1.0177x over previous
//
#include <hip/hip_runtime.h>
#include <math.h>

#define BB 4
#define TT 2048
#define EE 384
#define HH 6
#define DD 64
#define MM (BB*TT)   // 8192 tokens

typedef __attribute__((ext_vector_type(8))) short bf16x8;
typedef __attribute__((ext_vector_type(4))) float f32x4;

__device__ __forceinline__ unsigned short f2bf(float f) {
    unsigned int u = __float_as_uint(f);
    u = (u + 0x7FFFu + ((u >> 16) & 1u)) >> 16;   // RNE
    return (unsigned short)u;
}
__device__ __forceinline__ unsigned int pk2(float a, float b) {
    return (unsigned int)f2bf(a) | ((unsigned int)f2bf(b) << 16);
}

// ---------------- fp32 -> bf16 conversion: x (3072 blocks) + 4 weights (144 each) -----
__global__ __launch_bounds__(256) void k_cvt(const float* __restrict__ x,
                                             const float* __restrict__ wq,
                                             const float* __restrict__ wo,
                                             const float* __restrict__ w1,
                                             const float* __restrict__ w2,
                                             unsigned short* __restrict__ xb,
                                             unsigned short* __restrict__ wqb,
                                             unsigned short* __restrict__ wob,
                                             unsigned short* __restrict__ w1b,
                                             unsigned short* __restrict__ w2b)
{
    int bid = blockIdx.x;
    const float* src; unsigned short* dst; int i;
    if (bid < 3072)       { src = x;  dst = xb;  i = bid * 256; }
    else {
        int r = bid - 3072, wi = r / 144, off = (r % 144) * 256;
        const float* s4[4] = {wq, wo, w1, w2};
        unsigned short* d4[4] = {wqb, wob, w1b, w2b};
        src = s4[wi]; dst = d4[wi]; i = off;
    }
    i += threadIdx.x;
    float4 v = ((const float4*)src)[i];
    uint2 o; o.x = pk2(v.x, v.y); o.y = pk2(v.z, v.w);
    ((uint2*)dst)[i] = o;
}

// ---------------- MFMA GEMM: C[m,n] = A[m,:].W[n,:] (+bias, relu), bf16 in fp32 acc ---
// A bf16 [M,384], W bf16 [N,384]. Block 32m x 192n, 4 waves (16m x 96n each), no LDS.
// flags: 1=relu, 2=bf16 out, 4=qlayout (bf16 q[b,h,t,d])
__global__ __launch_bounds__(256, 2) void k_mgemm(const unsigned short* __restrict__ A,
                                                  const unsigned short* __restrict__ W,
                                                  const float* __restrict__ bias,
                                                  void* __restrict__ Cout, int flags)
{
    const int tid = threadIdx.x;
    const int w = tid >> 6, lane = tid & 63;
    const int fr = lane & 15, quad = lane >> 4;
    const int m0 = blockIdx.x * 32 + (w & 1) * 16;
    const int n0 = blockIdx.y * 192 + (w >> 1) * 96;
    const unsigned short* Ap = A + (size_t)(m0 + fr) * EE + quad * 8;
    const unsigned short* Wp = W + (size_t)(n0 + fr) * EE + quad * 8;

    f32x4 acc[6];
    #pragma unroll
    for (int nt = 0; nt < 6; nt++) acc[nt] = (f32x4){0.f, 0.f, 0.f, 0.f};

    #pragma unroll
    for (int k0 = 0; k0 < 12; k0++) {
        bf16x8 a = *(const bf16x8*)(Ap + k0 * 32);
        #pragma unroll
        for (int nt = 0; nt < 6; nt++) {
            bf16x8 b = *(const bf16x8*)(Wp + (size_t)nt * 16 * EE + k0 * 32);
            acc[nt] = __builtin_amdgcn_mfma_f32_16x16x32_bf16(a, b, acc[nt], 0, 0, 0);
        }
    }

    const int mrow = m0 + quad * 4;
    #pragma unroll
    for (int nt = 0; nt < 6; nt++) {
        int n = n0 + nt * 16 + fr;
        float bv = bias ? bias[n] : 0.0f;
        #pragma unroll
        for (int r = 0; r < 4; r++) {
            int m = mrow + r;
            float v = acc[nt][r] + bv;
            if (flags & 1) v = fmaxf(v, 0.0f);
            if (flags & 4) {          // q[b,h,t,d] bf16
                int b = m >> 11, t = m & 2047, h = n >> 6, d = n & 63;
                ((unsigned short*)Cout)[((size_t)(b * HH + h) * TT + t) * DD + d] = f2bf(v);
            } else if (flags & 2) {   // bf16 row-major
                ((unsigned short*)Cout)[(size_t)m * EE + n] = f2bf(v);
            } else {                  // fp32 row-major
                ((float*)Cout)[(size_t)m * EE + n] = v;
            }
        }
    }
}

// ---------------- transpose qbf[b,h,t,d] -> qbfT[b,h,d,t] (bf16) ----------------
__global__ __launch_bounds__(256) void k_prep(const unsigned short* __restrict__ qbf,
                                              unsigned short* __restrict__ qbfT)
{
    __shared__ unsigned short Ls[64][72];
    const int bh = blockIdx.y;
    const int t0 = blockIdx.x * 64;
    const unsigned short* src = qbf + ((size_t)bh * TT + t0) * DD;
    {
        int r = threadIdx.x >> 2, c = (threadIdx.x & 3) * 16;
        const unsigned short* p = src + (size_t)r * DD + c;
        *(uint4*)&Ls[r][c]     = *(const uint4*)(p);
        *(uint4*)&Ls[r][c + 8] = *(const uint4*)(p + 8);
    }
    __syncthreads();
    {
        int d = threadIdx.x >> 2, tc = (threadIdx.x & 3) * 16;
        unsigned short tmp[16];
        #pragma unroll
        for (int i = 0; i < 16; i++) tmp[i] = Ls[tc + i][d];
        unsigned short* dst = qbfT + ((size_t)bh * DD + d) * TT + t0 + tc;
        *(uint4*)(dst)     = *(const uint4*)&tmp[0];
        *(uint4*)(dst + 8) = *(const uint4*)&tmp[8];
    }
}

// ---------------- MFMA flash attention (q = k = v), causal + exact-zero quirk --------
// Causal pairing: block (p, bh) processes q-tiles p and 31-p => exactly 33 key-tile
// iterations per block (load-balanced under any dispatch->CU mapping).
// Softmax body is the R4-verified online-max version (kept byte-identical).
__global__ __launch_bounds__(256, 4) void k_attn(const unsigned short* __restrict__ qbf,
                                                 const unsigned short* __restrict__ qbfT,
                                                 unsigned short* __restrict__ cat)
{
    __shared__ unsigned short Qs[64][72];   // [q][d]
    __shared__ unsigned short Ks[64][72];   // [key][d]
    __shared__ unsigned short Vs[64][72];   // [d][key]
    __shared__ unsigned short Ps[64][72];   // [q][key] (wave-private rows)
    const int p = blockIdx.x;               // 0..15
    const int bh = blockIdx.y;              // 0..23
    const int bb = bh / HH, hh = bh % HH;
    const int tid = threadIdx.x;
    const int w = tid >> 6, lane = tid & 63;
    const int fr = lane & 15;
    const int fc = (lane >> 4) * 8;
    const unsigned short* qb  = qbf  + (size_t)bh * TT * DD;
    const unsigned short* qtb = qbfT + (size_t)bh * DD * TT;
    const int lr = tid >> 2, lc = (tid & 3) * 16;

    #pragma unroll 1
    for (int ph = 0; ph < 2; ph++) {
        const int tile = ph ? (31 - p) : p;
        const int m0 = tile * 64;

        __syncthreads();   // all phase-1 reads done before Qs overwrite
        {
            const unsigned short* qp = qb + (size_t)(m0 + lr) * DD + lc;
            *(uint4*)&Qs[lr][lc]     = *(const uint4*)(qp);
            *(uint4*)&Qs[lr][lc + 8] = *(const uint4*)(qp + 8);
        }
        __syncthreads();
        const bf16x8 qA0 = *(const bf16x8*)&Qs[w * 16 + fr][fc];
        const bf16x8 qA1 = *(const bf16x8*)&Qs[w * 16 + fr][fc + 32];

        f32x4 accO[4];
        #pragma unroll
        for (int dt = 0; dt < 4; dt++) accO[dt] = (f32x4){0.f, 0.f, 0.f, 0.f};
        float mi[4], li[4];
        #pragma unroll
        for (int r = 0; r < 4; r++) { mi[r] = -INFINITY; li[r] = 0.0f; }
        const int rowbase = m0 + w * 16 + (lane >> 4) * 4;

        for (int kt = 0; kt <= tile; kt++) {
            const int s0 = kt * 64;
            __syncthreads();
            {
                const unsigned short* kp = qb + (size_t)(s0 + lr) * DD + lc;
                *(uint4*)&Ks[lr][lc]     = *(const uint4*)(kp);
                *(uint4*)&Ks[lr][lc + 8] = *(const uint4*)(kp + 8);
                const unsigned short* vp = qtb + (size_t)lr * TT + s0 + lc;
                *(uint4*)&Vs[lr][lc]     = *(const uint4*)(vp);
                *(uint4*)&Vs[lr][lc + 8] = *(const uint4*)(vp + 8);
            }
            __syncthreads();

            f32x4 S[4];
            #pragma unroll
            for (int nt = 0; nt < 4; nt++) {
                f32x4 acc = (f32x4){0.f, 0.f, 0.f, 0.f};
                bf16x8 b0 = *(const bf16x8*)&Ks[nt * 16 + fr][fc];
                acc = __builtin_amdgcn_mfma_f32_16x16x32_bf16(qA0, b0, acc, 0, 0, 0);
                bf16x8 b1 = *(const bf16x8*)&Ks[nt * 16 + fr][fc + 32];
                acc = __builtin_amdgcn_mfma_f32_16x16x32_bf16(qA1, b1, acc, 0, 0, 0);
                S[nt] = acc;
            }

            float mx[4] = {-INFINITY, -INFINITY, -INFINITY, -INFINITY};
            #pragma unroll
            for (int nt = 0; nt < 4; nt++) {
                int jg = s0 + nt * 16 + fr;
                #pragma unroll
                for (int r = 0; r < 4; r++) {
                    float v = S[nt][r] * 0.125f;
                    v = (jg <= rowbase + r) ? v : 0.0f;
                    v = (v == 0.0f) ? -INFINITY : v;
                    S[nt][r] = v;
                    mx[r] = fmaxf(mx[r], v);
                }
            }
            #pragma unroll
            for (int r = 0; r < 4; r++) {
                #pragma unroll
                for (int o = 1; o < 16; o <<= 1) mx[r] = fmaxf(mx[r], __shfl_xor(mx[r], o, 64));
            }

            float al[4], ls[4];
            #pragma unroll
            for (int r = 0; r < 4; r++) {
                float mnew = fmaxf(mi[r], mx[r]);
                al[r] = (mnew == -INFINITY) ? 1.0f : __expf(mi[r] - mnew);
                mi[r] = mnew;
                ls[r] = 0.0f;
            }
            #pragma unroll
            for (int nt = 0; nt < 4; nt++) {
                #pragma unroll
                for (int r = 0; r < 4; r++) {
                    float v = S[nt][r];
                    float pv = (v == -INFINITY) ? 0.0f : __expf(v - mi[r]);
                    ls[r] += pv;
                    Ps[w * 16 + (lane >> 4) * 4 + r][nt * 16 + fr] = f2bf(pv);
                }
            }
            #pragma unroll
            for (int r = 0; r < 4; r++) {
                #pragma unroll
                for (int o = 1; o < 16; o <<= 1) ls[r] += __shfl_xor(ls[r], o, 64);
                li[r] = li[r] * al[r] + ls[r];
            }
            #pragma unroll
            for (int dt = 0; dt < 4; dt++)
                #pragma unroll
                for (int r = 0; r < 4; r++) accO[dt][r] *= al[r];

            bf16x8 pA0 = *(const bf16x8*)&Ps[w * 16 + fr][fc];
            bf16x8 pA1 = *(const bf16x8*)&Ps[w * 16 + fr][fc + 32];
            #pragma unroll
            for (int dt = 0; dt < 4; dt++) {
                bf16x8 v0 = *(const bf16x8*)&Vs[dt * 16 + fr][fc];
                accO[dt] = __builtin_amdgcn_mfma_f32_16x16x32_bf16(pA0, v0, accO[dt], 0, 0, 0);
                bf16x8 v1 = *(const bf16x8*)&Vs[dt * 16 + fr][fc + 32];
                accO[dt] = __builtin_amdgcn_mfma_f32_16x16x32_bf16(pA1, v1, accO[dt], 0, 0, 0);
            }
        }

        float inv[4];
        #pragma unroll
        for (int r = 0; r < 4; r++) inv[r] = 1.0f / li[r];
        #pragma unroll
        for (int dt = 0; dt < 4; dt++) {
            #pragma unroll
            for (int r = 0; r < 4; r++) {
                int t = rowbase + r;
                cat[((size_t)bb * TT + t) * EE + hh * DD + dt * 16 + fr] =
                    f2bf(accO[dt][r] * inv[r]);
            }
        }
    }
}

// ---------------- LayerNorm: out = LN(x + pre) fp32 (+ optional bf16 copy) -----------
__global__ __launch_bounds__(256) void k_ln(const float* __restrict__ x,
                                            const float* __restrict__ pre,
                                            const float* __restrict__ g,
                                            const float* __restrict__ be,
                                            float* __restrict__ out,
                                            unsigned short* __restrict__ obf)
{
    const int w = threadIdx.x >> 6, l = threadIdx.x & 63;
    const int m = blockIdx.x * 4 + w;
    const float* xp = x + (size_t)m * EE;
    const float* pp = pre + (size_t)m * EE;
    float v[6], s = 0.0f, s2 = 0.0f;
    #pragma unroll
    for (int i = 0; i < 6; i++) {
        int e = l + 64 * i;
        float a = xp[e] + pp[e];
        v[i] = a; s += a; s2 += a * a;
    }
    #pragma unroll
    for (int o = 1; o < 64; o <<= 1) { s += __shfl_xor(s, o, 64); s2 += __shfl_xor(s2, o, 64); }
    float mu = s * (1.0f / EE);
    float var = s2 * (1.0f / EE) - mu * mu;
    float rs = rsqrtf(var + 1e-5f);
    float* op = out + (size_t)m * EE;
    unsigned short* ob = obf ? obf + (size_t)m * EE : nullptr;
    #pragma unroll
    for (int i = 0; i < 6; i++) {
        int e = l + 64 * i;
        float r = (v[i] - mu) * rs * g[e] + be[e];
        op[e] = r;
        if (ob) ob[e] = f2bf(r);
    }
}

extern "C" void kernel_launch(void* const* d_in, const int* in_sizes, int n_in,
                              void* d_out, int out_size, void* d_ws, size_t ws_size,
                              hipStream_t stream) {
    (void)in_sizes; (void)n_in; (void)out_size; (void)ws_size;
    const float* x   = (const float*)d_in[0];
    const float* Wq  = (const float*)d_in[1];
    const float* Wo  = (const float*)d_in[2];
    const float* bo  = (const float*)d_in[3];
    const float* W1  = (const float*)d_in[4];
    const float* b1  = (const float*)d_in[5];
    const float* W2  = (const float*)d_in[6];
    const float* b2  = (const float*)d_in[7];
    const float* g1  = (const float*)d_in[8];
    const float* be1 = (const float*)d_in[9];
    const float* g2  = (const float*)d_in[10];
    const float* be2 = (const float*)d_in[11];
    float* out = (float*)d_out;

    float* ws = (float*)d_ws;
    const size_t SZ = (size_t)MM * EE;    // 3,145,728 floats / region (12.6 MB)
    float* S0 = ws;                        // sa fp32
    float* S1 = ws + SZ;                   // qbf|qbfT (bf16), later x1 fp32
    float* S2 = ws + 2 * SZ;               // catbf (bf16), later ff fp32
    float* S3 = ws + 3 * SZ;               // xbf / x1bf + weight bf16 copies

    unsigned short* qbf  = (unsigned short*)S1;
    unsigned short* qbfT = qbf + (size_t)MM * DD;
    unsigned short* catb = (unsigned short*)S2;
    unsigned short* xbf  = (unsigned short*)S3;
    unsigned short* wqb  = xbf + SZ;
    unsigned short* wob  = wqb + (size_t)EE * EE;
    unsigned short* w1b  = wob + (size_t)EE * EE;
    unsigned short* w2b  = w1b + (size_t)EE * EE;
    unsigned short* h1b  = (unsigned short*)out;

    k_cvt<<<dim3(3072 + 4 * 144), dim3(256), 0, stream>>>(x, Wq, Wo, W1, W2,
                                                          xbf, wqb, wob, w1b, w2b);
    k_mgemm<<<dim3(MM / 32, 2), dim3(256), 0, stream>>>(xbf, wqb, nullptr, qbf, 4);
    k_prep<<<dim3(TT / 64, BB * HH), dim3(256), 0, stream>>>(qbf, qbfT);
    k_attn<<<dim3(16, BB * HH), dim3(256), 0, stream>>>(qbf, qbfT, catb);
    k_mgemm<<<dim3(MM / 32, 2), dim3(256), 0, stream>>>(catb, wob, bo, S0, 0);
    k_ln<<<dim3(MM / 4), dim3(256), 0, stream>>>(x, S0, g1, be1, S1, xbf);
    k_mgemm<<<dim3(MM / 32, 2), dim3(256), 0, stream>>>(xbf, w1b, b1, h1b, 1 | 2);
    k_mgemm<<<dim3(MM / 32, 2), dim3(256), 0, stream>>>(h1b, w2b, b2, S2, 0);
    k_ln<<<dim3(MM / 4), dim3(256), 0, stream>>>(S1, S2, g2, be2, out, nullptr);
}

// Round 8
// 276.887 us; speedup vs baseline: 2.5590x; 1.0636x over previous
//
#include <hip/hip_runtime.h>
#include <math.h>

#define BB 4
#define TT 2048
#define EE 384
#define HH 6
#define DD 64
#define MM (BB*TT)   // 8192 tokens

typedef __attribute__((ext_vector_type(8))) short bf16x8;
typedef __attribute__((ext_vector_type(4))) float f32x4;

__device__ __forceinline__ unsigned short f2bf(float f) {
    unsigned int u = __float_as_uint(f);
    u = (u + 0x7FFFu + ((u >> 16) & 1u)) >> 16;   // RNE
    return (unsigned short)u;
}
__device__ __forceinline__ unsigned int pk2(float a, float b) {
    return (unsigned int)f2bf(a) | ((unsigned int)f2bf(b) << 16);
}

// ---------------- fp32 -> bf16 conversion: x (3072 blocks) + 4 weights (144 each) -----
__global__ __launch_bounds__(256) void k_cvt(const float* __restrict__ x,
                                             const float* __restrict__ wq,
                                             const float* __restrict__ wo,
                                             const float* __restrict__ w1,
                                             const float* __restrict__ w2,
                                             unsigned short* __restrict__ xb,
                                             unsigned short* __restrict__ wqb,
                                             unsigned short* __restrict__ wob,
                                             unsigned short* __restrict__ w1b,
                                             unsigned short* __restrict__ w2b)
{
    int bid = blockIdx.x;
    const float* src; unsigned short* dst; int i;
    if (bid < 3072)       { src = x;  dst = xb;  i = bid * 256; }
    else {
        int r = bid - 3072, wi = r / 144, off = (r % 144) * 256;
        const float* s4[4] = {wq, wo, w1, w2};
        unsigned short* d4[4] = {wqb, wob, w1b, w2b};
        src = s4[wi]; dst = d4[wi]; i = off;
    }
    i += threadIdx.x;
    float4 v = ((const float4*)src)[i];
    uint2 o; o.x = pk2(v.x, v.y); o.y = pk2(v.z, v.w);
    ((uint2*)dst)[i] = o;
}

// ---------------- MFMA GEMM: C[m,n] = A[m,:].W[n,:] (+bias, relu), bf16 in fp32 acc ---
// Block 16m x 192n, 4 waves (each 16m x 48n, 3 acc tiles), no LDS, grid 1024 =>
// 4 blocks/CU, 16 waves/CU for latency hiding.
// flags: 1=relu, 2=bf16 out, 4=qlayout (writes qbf[b,h,t,d] AND qbfT[b,h,d,t])
__global__ __launch_bounds__(256, 4) void k_mgemm(const unsigned short* __restrict__ A,
                                                  const unsigned short* __restrict__ W,
                                                  const float* __restrict__ bias,
                                                  void* __restrict__ Cout,
                                                  unsigned short* __restrict__ CoutT,
                                                  int flags)
{
    const int tid = threadIdx.x;
    const int w = tid >> 6, lane = tid & 63;
    const int fr = lane & 15, quad = lane >> 4;
    const int m0 = blockIdx.x * 16;
    const int n0 = blockIdx.y * 192 + w * 48;
    const unsigned short* Ap = A + (size_t)(m0 + fr) * EE + quad * 8;
    const unsigned short* Wp = W + (size_t)(n0 + fr) * EE + quad * 8;

    f32x4 acc[3];
    #pragma unroll
    for (int nt = 0; nt < 3; nt++) acc[nt] = (f32x4){0.f, 0.f, 0.f, 0.f};

    #pragma unroll
    for (int k0 = 0; k0 < 12; k0++) {
        bf16x8 a = *(const bf16x8*)(Ap + k0 * 32);
        #pragma unroll
        for (int nt = 0; nt < 3; nt++) {
            bf16x8 b = *(const bf16x8*)(Wp + (size_t)nt * 16 * EE + k0 * 32);
            acc[nt] = __builtin_amdgcn_mfma_f32_16x16x32_bf16(a, b, acc[nt], 0, 0, 0);
        }
    }

    const int mrow = m0 + quad * 4;
    #pragma unroll
    for (int nt = 0; nt < 3; nt++) {
        int n = n0 + nt * 16 + fr;
        float bv = bias ? bias[n] : 0.0f;
        #pragma unroll
        for (int r = 0; r < 4; r++) {
            int m = mrow + r;
            float v = acc[nt][r] + bv;
            if (flags & 1) v = fmaxf(v, 0.0f);
            if (flags & 4) {          // q[b,h,t,d] + transposed q[b,h,d,t], bf16
                int b = m >> 11, t = m & 2047, h = n >> 6, d = n & 63;
                unsigned short bf = f2bf(v);
                ((unsigned short*)Cout)[((size_t)(b * HH + h) * TT + t) * DD + d] = bf;
                CoutT[((size_t)(b * HH + h) * DD + d) * TT + t] = bf;
            } else if (flags & 2) {   // bf16 row-major
                ((unsigned short*)Cout)[(size_t)m * EE + n] = f2bf(v);
            } else {                  // fp32 row-major
                ((float*)Cout)[(size_t)m * EE + n] = v;
            }
        }
    }
}

// ---------------- MFMA flash attention (q = k = v), causal + exact-zero quirk --------
// Causal pairing (tiles p and 31-p => 33 iters/block) + REGISTER DOUBLE-BUFFER:
// next key-tile's K/V global loads issue right after staging the current tile, so
// global-load latency overlaps a full iteration of compute instead of barrier-1.
// Softmax body is the R4/R6-verified online-max version (numerics unchanged).
__global__ __launch_bounds__(256, 4) void k_attn(const unsigned short* __restrict__ qbf,
                                                 const unsigned short* __restrict__ qbfT,
                                                 unsigned short* __restrict__ cat)
{
    __shared__ unsigned short Qs[64][72];   // [q][d]
    __shared__ unsigned short Ks[64][72];   // [key][d]
    __shared__ unsigned short Vs[64][72];   // [d][key]
    __shared__ unsigned short Ps[64][72];   // [q][key] (wave-private rows)
    const int p = blockIdx.x;               // 0..15
    const int bh = blockIdx.y;              // 0..23
    const int bb = bh / HH, hh = bh % HH;
    const int tid = threadIdx.x;
    const int w = tid >> 6, lane = tid & 63;
    const int fr = lane & 15;
    const int fc = (lane >> 4) * 8;
    const unsigned short* qb  = qbf  + (size_t)bh * TT * DD;
    const unsigned short* qtb = qbfT + (size_t)bh * DD * TT;
    const int lr = tid >> 2, lc = (tid & 3) * 16;

    #pragma unroll 1
    for (int ph = 0; ph < 2; ph++) {
        const int tile = ph ? (31 - p) : p;
        const int m0 = tile * 64;

        // prefetch key-tile 0 into registers (overlaps Q staging)
        uint4 kr0, kr1, vr0, vr1;
        {
            const unsigned short* kp = qb + (size_t)lr * DD + lc;
            kr0 = *(const uint4*)(kp);
            kr1 = *(const uint4*)(kp + 8);
            const unsigned short* vp = qtb + (size_t)lr * TT + lc;
            vr0 = *(const uint4*)(vp);
            vr1 = *(const uint4*)(vp + 8);
        }

        __syncthreads();   // all previous-phase reads done before Qs overwrite
        {
            const unsigned short* qp = qb + (size_t)(m0 + lr) * DD + lc;
            *(uint4*)&Qs[lr][lc]     = *(const uint4*)(qp);
            *(uint4*)&Qs[lr][lc + 8] = *(const uint4*)(qp + 8);
        }
        __syncthreads();
        const bf16x8 qA0 = *(const bf16x8*)&Qs[w * 16 + fr][fc];
        const bf16x8 qA1 = *(const bf16x8*)&Qs[w * 16 + fr][fc + 32];

        f32x4 accO[4];
        #pragma unroll
        for (int dt = 0; dt < 4; dt++) accO[dt] = (f32x4){0.f, 0.f, 0.f, 0.f};
        float mi[4], li[4];
        #pragma unroll
        for (int r = 0; r < 4; r++) { mi[r] = -INFINITY; li[r] = 0.0f; }
        const int rowbase = m0 + w * 16 + (lane >> 4) * 4;

        for (int kt = 0; kt <= tile; kt++) {
            const int s0 = kt * 64;
            __syncthreads();   // prev iteration's LDS reads (Ks/Vs/Ps) complete
            // stage current tile from registers
            *(uint4*)&Ks[lr][lc]     = kr0;
            *(uint4*)&Ks[lr][lc + 8] = kr1;
            *(uint4*)&Vs[lr][lc]     = vr0;
            *(uint4*)&Vs[lr][lc + 8] = vr1;
            // prefetch next tile (latency hidden behind this iteration's compute)
            if (kt < tile) {
                const unsigned short* kp = qb + (size_t)(s0 + 64 + lr) * DD + lc;
                kr0 = *(const uint4*)(kp);
                kr1 = *(const uint4*)(kp + 8);
                const unsigned short* vp = qtb + (size_t)lr * TT + s0 + 64 + lc;
                vr0 = *(const uint4*)(vp);
                vr1 = *(const uint4*)(vp + 8);
            }
            __syncthreads();   // staged tile visible

            f32x4 S[4];
            #pragma unroll
            for (int nt = 0; nt < 4; nt++) {
                f32x4 acc = (f32x4){0.f, 0.f, 0.f, 0.f};
                bf16x8 b0 = *(const bf16x8*)&Ks[nt * 16 + fr][fc];
                acc = __builtin_amdgcn_mfma_f32_16x16x32_bf16(qA0, b0, acc, 0, 0, 0);
                bf16x8 b1 = *(const bf16x8*)&Ks[nt * 16 + fr][fc + 32];
                acc = __builtin_amdgcn_mfma_f32_16x16x32_bf16(qA1, b1, acc, 0, 0, 0);
                S[nt] = acc;
            }

            float mx[4] = {-INFINITY, -INFINITY, -INFINITY, -INFINITY};
            #pragma unroll
            for (int nt = 0; nt < 4; nt++) {
                int jg = s0 + nt * 16 + fr;
                #pragma unroll
                for (int r = 0; r < 4; r++) {
                    float v = S[nt][r] * 0.125f;
                    v = (jg <= rowbase + r) ? v : 0.0f;
                    v = (v == 0.0f) ? -INFINITY : v;
                    S[nt][r] = v;
                    mx[r] = fmaxf(mx[r], v);
                }
            }
            #pragma unroll
            for (int r = 0; r < 4; r++) {
                #pragma unroll
                for (int o = 1; o < 16; o <<= 1) mx[r] = fmaxf(mx[r], __shfl_xor(mx[r], o, 64));
            }

            float al[4], ls[4];
            #pragma unroll
            for (int r = 0; r < 4; r++) {
                float mnew = fmaxf(mi[r], mx[r]);
                al[r] = (mnew == -INFINITY) ? 1.0f : __expf(mi[r] - mnew);
                mi[r] = mnew;
                ls[r] = 0.0f;
            }
            #pragma unroll
            for (int nt = 0; nt < 4; nt++) {
                #pragma unroll
                for (int r = 0; r < 4; r++) {
                    float v = S[nt][r];
                    float pv = (v == -INFINITY) ? 0.0f : __expf(v - mi[r]);
                    ls[r] += pv;
                    Ps[w * 16 + (lane >> 4) * 4 + r][nt * 16 + fr] = f2bf(pv);
                }
            }
            #pragma unroll
            for (int r = 0; r < 4; r++) {
                #pragma unroll
                for (int o = 1; o < 16; o <<= 1) ls[r] += __shfl_xor(ls[r], o, 64);
                li[r] = li[r] * al[r] + ls[r];
            }
            #pragma unroll
            for (int dt = 0; dt < 4; dt++)
                #pragma unroll
                for (int r = 0; r < 4; r++) accO[dt][r] *= al[r];

            bf16x8 pA0 = *(const bf16x8*)&Ps[w * 16 + fr][fc];
            bf16x8 pA1 = *(const bf16x8*)&Ps[w * 16 + fr][fc + 32];
            #pragma unroll
            for (int dt = 0; dt < 4; dt++) {
                bf16x8 v0 = *(const bf16x8*)&Vs[dt * 16 + fr][fc];
                accO[dt] = __builtin_amdgcn_mfma_f32_16x16x32_bf16(pA0, v0, accO[dt], 0, 0, 0);
                bf16x8 v1 = *(const bf16x8*)&Vs[dt * 16 + fr][fc + 32];
                accO[dt] = __builtin_amdgcn_mfma_f32_16x16x32_bf16(pA1, v1, accO[dt], 0, 0, 0);
            }
        }

        float inv[4];
        #pragma unroll
        for (int r = 0; r < 4; r++) inv[r] = 1.0f / li[r];
        #pragma unroll
        for (int dt = 0; dt < 4; dt++) {
            #pragma unroll
            for (int r = 0; r < 4; r++) {
                int t = rowbase + r;
                cat[((size_t)bb * TT + t) * EE + hh * DD + dt * 16 + fr] =
                    f2bf(accO[dt][r] * inv[r]);
            }
        }
    }
}

// ---------------- LayerNorm: out = LN(x + pre) fp32 (+ optional bf16 copy) -----------
__global__ __launch_bounds__(256) void k_ln(const float* __restrict__ x,
                                            const float* __restrict__ pre,
                                            const float* __restrict__ g,
                                            const float* __restrict__ be,
                                            float* __restrict__ out,
                                            unsigned short* __restrict__ obf)
{
    const int w = threadIdx.x >> 6, l = threadIdx.x & 63;
    const int m = blockIdx.x * 4 + w;
    const float* xp = x + (size_t)m * EE;
    const float* pp = pre + (size_t)m * EE;
    float v[6], s = 0.0f, s2 = 0.0f;
    #pragma unroll
    for (int i = 0; i < 6; i++) {
        int e = l + 64 * i;
        float a = xp[e] + pp[e];
        v[i] = a; s += a; s2 += a * a;
    }
    #pragma unroll
    for (int o = 1; o < 64; o <<= 1) { s += __shfl_xor(s, o, 64); s2 += __shfl_xor(s2, o, 64); }
    float mu = s * (1.0f / EE);
    float var = s2 * (1.0f / EE) - mu * mu;
    float rs = rsqrtf(var + 1e-5f);
    float* op = out + (size_t)m * EE;
    unsigned short* ob = obf ? obf + (size_t)m * EE : nullptr;
    #pragma unroll
    for (int i = 0; i < 6; i++) {
        int e = l + 64 * i;
        float r = (v[i] - mu) * rs * g[e] + be[e];
        op[e] = r;
        if (ob) ob[e] = f2bf(r);
    }
}

extern "C" void kernel_launch(void* const* d_in, const int* in_sizes, int n_in,
                              void* d_out, int out_size, void* d_ws, size_t ws_size,
                              hipStream_t stream) {
    (void)in_sizes; (void)n_in; (void)out_size; (void)ws_size;
    const float* x   = (const float*)d_in[0];
    const float* Wq  = (const float*)d_in[1];
    const float* Wo  = (const float*)d_in[2];
    const float* bo  = (const float*)d_in[3];
    const float* W1  = (const float*)d_in[4];
    const float* b1  = (const float*)d_in[5];
    const float* W2  = (const float*)d_in[6];
    const float* b2  = (const float*)d_in[7];
    const float* g1  = (const float*)d_in[8];
    const float* be1 = (const float*)d_in[9];
    const float* g2  = (const float*)d_in[10];
    const float* be2 = (const float*)d_in[11];
    float* out = (float*)d_out;

    float* ws = (float*)d_ws;
    const size_t SZ = (size_t)MM * EE;    // 3,145,728 floats / region (12.6 MB)
    float* S0 = ws;                        // sa fp32
    float* S1 = ws + SZ;                   // qbf|qbfT (bf16), later x1 fp32
    float* S2 = ws + 2 * SZ;               // catbf (bf16), later ff fp32
    float* S3 = ws + 3 * SZ;               // xbf / x1bf + weight bf16 copies

    unsigned short* qbf  = (unsigned short*)S1;
    // qbf is B*H*T*D = 3,145,728 ushorts. qbfT MUST start after ALL of it.
    // (R5/R6 had qbfT = qbf + MM*DD = +524288 -> qbfT[bh] aliased qbf[bh+4]:
    //  the race behind R5's replay-only failure and R7's deterministic corruption.)
    unsigned short* qbfT = qbf + (size_t)BB * HH * TT * DD;   // qbf+qbfT fill S1 exactly
    unsigned short* catb = (unsigned short*)S2;
    unsigned short* xbf  = (unsigned short*)S3;
    unsigned short* wqb  = xbf + SZ;
    unsigned short* wob  = wqb + (size_t)EE * EE;
    unsigned short* w1b  = wob + (size_t)EE * EE;
    unsigned short* w2b  = w1b + (size_t)EE * EE;
    unsigned short* h1b  = (unsigned short*)out;

    k_cvt<<<dim3(3072 + 4 * 144), dim3(256), 0, stream>>>(x, Wq, Wo, W1, W2,
                                                          xbf, wqb, wob, w1b, w2b);
    k_mgemm<<<dim3(MM / 16, 2), dim3(256), 0, stream>>>(xbf, wqb, nullptr, qbf, qbfT, 4);
    k_attn<<<dim3(16, BB * HH), dim3(256), 0, stream>>>(qbf, qbfT, catb);
    k_mgemm<<<dim3(MM / 16, 2), dim3(256), 0, stream>>>(catb, wob, bo, S0, nullptr, 0);
    k_ln<<<dim3(MM / 4), dim3(256), 0, stream>>>(x, S0, g1, be1, S1, xbf);
    k_mgemm<<<dim3(MM / 16, 2), dim3(256), 0, stream>>>(xbf, w1b, b1, h1b, nullptr, 1 | 2);
    k_mgemm<<<dim3(MM / 16, 2), dim3(256), 0, stream>>>(h1b, w2b, b2, S2, nullptr, 0);
    k_ln<<<dim3(MM / 4), dim3(256), 0, stream>>>(S1, S2, g2, be2, out, nullptr);
}

// Round 9
// 233.914 us; speedup vs baseline: 3.0291x; 1.1837x over previous
//
#include <hip/hip_runtime.h>
#include <math.h>

#define BB 4
#define TT 2048
#define EE 384
#define HH 6
#define DD 64
#define MM (BB*TT)   // 8192 tokens

typedef __attribute__((ext_vector_type(8))) short bf16x8;
typedef __attribute__((ext_vector_type(4))) float f32x4;

__device__ __forceinline__ unsigned short f2bf(float f) {
    unsigned int u = __float_as_uint(f);
    u = (u + 0x7FFFu + ((u >> 16) & 1u)) >> 16;   // RNE
    return (unsigned short)u;
}
__device__ __forceinline__ unsigned int pk2(float a, float b) {
    return (unsigned int)f2bf(a) | ((unsigned int)f2bf(b) << 16);
}

// ---------------- fp32 -> bf16 conversion: weights only (4 x 144 blocks) -------------
__global__ __launch_bounds__(256) void k_cvt(const float* __restrict__ wq,
                                             const float* __restrict__ wo,
                                             const float* __restrict__ w1,
                                             const float* __restrict__ w2,
                                             unsigned short* __restrict__ wqb,
                                             unsigned short* __restrict__ wob,
                                             unsigned short* __restrict__ w1b,
                                             unsigned short* __restrict__ w2b)
{
    int wi = blockIdx.x / 144, off = (blockIdx.x % 144) * 256;
    const float* s4[4] = {wq, wo, w1, w2};
    unsigned short* d4[4] = {wqb, wob, w1b, w2b};
    const float* src = s4[wi]; unsigned short* dst = d4[wi];
    int i = off + threadIdx.x;
    float4 v = ((const float4*)src)[i];
    uint2 o; o.x = pk2(v.x, v.y); o.y = pk2(v.z, v.w);
    ((uint2*)dst)[i] = o;
}

// ---------------- q-GEMM: A fp32 (packed in-register), writes qbf + qbfT bf16 --------
// Block 16m x 192n, 4 waves x 48n (3 acc tiles), grid (512,2) => 4 blocks/CU.
__global__ __launch_bounds__(256, 4) void k_qgemm(const float* __restrict__ A,
                                                  const unsigned short* __restrict__ W,
                                                  unsigned short* __restrict__ qbf,
                                                  unsigned short* __restrict__ qbfT)
{
    const int tid = threadIdx.x;
    const int w = tid >> 6, lane = tid & 63;
    const int fr = lane & 15, quad = lane >> 4;
    const int m0 = blockIdx.x * 16;
    const int n0 = blockIdx.y * 192 + w * 48;
    const float* Ap = A + (size_t)(m0 + fr) * EE + quad * 8;
    const unsigned short* Wp = W + (size_t)(n0 + fr) * EE + quad * 8;

    f32x4 acc[3];
    #pragma unroll
    for (int nt = 0; nt < 3; nt++) acc[nt] = (f32x4){0.f, 0.f, 0.f, 0.f};

    #pragma unroll
    for (int k0 = 0; k0 < 12; k0++) {
        float4 a0 = *(const float4*)(Ap + k0 * 32);
        float4 a1 = *(const float4*)(Ap + k0 * 32 + 4);
        unsigned int ap[4];
        ap[0] = pk2(a0.x, a0.y); ap[1] = pk2(a0.z, a0.w);
        ap[2] = pk2(a1.x, a1.y); ap[3] = pk2(a1.z, a1.w);
        bf16x8 a = *(const bf16x8*)ap;
        #pragma unroll
        for (int nt = 0; nt < 3; nt++) {
            bf16x8 b = *(const bf16x8*)(Wp + (size_t)nt * 16 * EE + k0 * 32);
            acc[nt] = __builtin_amdgcn_mfma_f32_16x16x32_bf16(a, b, acc[nt], 0, 0, 0);
        }
    }

    const int mrow = m0 + quad * 4;
    #pragma unroll
    for (int nt = 0; nt < 3; nt++) {
        int n = n0 + nt * 16 + fr;
        int h = n >> 6, d = n & 63;
        #pragma unroll
        for (int r = 0; r < 4; r++) {
            int m = mrow + r;
            int b = m >> 11, t = m & 2047;
            unsigned short bf = f2bf(acc[nt][r]);
            qbf [((size_t)(b * HH + h) * TT + t) * DD + d] = bf;
            qbfT[((size_t)(b * HH + h) * DD + d) * TT + t] = bf;
        }
    }
}

// ---------------- MFMA GEMM (+bias,+relu), bf16 out: used for FFN1 -------------------
__global__ __launch_bounds__(256, 4) void k_mgemm(const unsigned short* __restrict__ A,
                                                  const unsigned short* __restrict__ W,
                                                  const float* __restrict__ bias,
                                                  unsigned short* __restrict__ Cout)
{
    const int tid = threadIdx.x;
    const int w = tid >> 6, lane = tid & 63;
    const int fr = lane & 15, quad = lane >> 4;
    const int m0 = blockIdx.x * 16;
    const int n0 = blockIdx.y * 192 + w * 48;
    const unsigned short* Ap = A + (size_t)(m0 + fr) * EE + quad * 8;
    const unsigned short* Wp = W + (size_t)(n0 + fr) * EE + quad * 8;

    f32x4 acc[3];
    #pragma unroll
    for (int nt = 0; nt < 3; nt++) acc[nt] = (f32x4){0.f, 0.f, 0.f, 0.f};

    #pragma unroll
    for (int k0 = 0; k0 < 12; k0++) {
        bf16x8 a = *(const bf16x8*)(Ap + k0 * 32);
        #pragma unroll
        for (int nt = 0; nt < 3; nt++) {
            bf16x8 b = *(const bf16x8*)(Wp + (size_t)nt * 16 * EE + k0 * 32);
            acc[nt] = __builtin_amdgcn_mfma_f32_16x16x32_bf16(a, b, acc[nt], 0, 0, 0);
        }
    }

    const int mrow = m0 + quad * 4;
    #pragma unroll
    for (int nt = 0; nt < 3; nt++) {
        int n = n0 + nt * 16 + fr;
        float bv = bias[n];
        #pragma unroll
        for (int r = 0; r < 4; r++) {
            float v = fmaxf(acc[nt][r] + bv, 0.0f);
            Cout[(size_t)(mrow + r) * EE + n] = f2bf(v);
        }
    }
}

// ---------------- fused GEMM + bias + residual + LayerNorm ---------------------------
// Block = 16 rows x FULL N=384 (4 waves x 96n, 6 acc tiles each) so the LN row
// reduction is block-local. outf (fp32) and/or outbf (bf16) written.
__global__ __launch_bounds__(256, 2) void k_pln(const unsigned short* __restrict__ A,
                                                const unsigned short* __restrict__ W,
                                                const float* __restrict__ bias,
                                                const float* __restrict__ resid,
                                                const float* __restrict__ g,
                                                const float* __restrict__ be,
                                                float* __restrict__ outf,
                                                unsigned short* __restrict__ outbf)
{
    __shared__ float ssum[16][4];
    __shared__ float ssq[16][4];
    const int tid = threadIdx.x;
    const int w = tid >> 6, lane = tid & 63;
    const int fr = lane & 15, quad = lane >> 4;
    const int m0 = blockIdx.x * 16;
    const int n0 = w * 96;
    const unsigned short* Ap = A + (size_t)(m0 + fr) * EE + quad * 8;
    const unsigned short* Wp = W + (size_t)(n0 + fr) * EE + quad * 8;

    f32x4 acc[6];
    #pragma unroll
    for (int nt = 0; nt < 6; nt++) acc[nt] = (f32x4){0.f, 0.f, 0.f, 0.f};

    #pragma unroll
    for (int k0 = 0; k0 < 12; k0++) {
        bf16x8 a = *(const bf16x8*)(Ap + k0 * 32);
        #pragma unroll
        for (int nt = 0; nt < 6; nt++) {
            bf16x8 b = *(const bf16x8*)(Wp + (size_t)nt * 16 * EE + k0 * 32);
            acc[nt] = __builtin_amdgcn_mfma_f32_16x16x32_bf16(a, b, acc[nt], 0, 0, 0);
        }
    }

    // val = acc + bias + resid (kept in acc regs); per-row partial sums
    float s1[4] = {0.f, 0.f, 0.f, 0.f}, s2[4] = {0.f, 0.f, 0.f, 0.f};
    #pragma unroll
    for (int nt = 0; nt < 6; nt++) {
        int n = n0 + nt * 16 + fr;
        float bv = bias[n];
        #pragma unroll
        for (int r = 0; r < 4; r++) {
            float v = acc[nt][r] + bv + resid[(size_t)(m0 + quad * 4 + r) * EE + n];
            acc[nt][r] = v;
            s1[r] += v;
            s2[r] += v * v;
        }
    }
    // reduce across the 16 fr-lanes of this quad (bits 0..3)
    #pragma unroll
    for (int r = 0; r < 4; r++) {
        #pragma unroll
        for (int o = 1; o < 16; o <<= 1) {
            s1[r] += __shfl_xor(s1[r], o, 64);
            s2[r] += __shfl_xor(s2[r], o, 64);
        }
    }
    if (fr == 0) {
        #pragma unroll
        for (int r = 0; r < 4; r++) {
            ssum[quad * 4 + r][w] = s1[r];
            ssq [quad * 4 + r][w] = s2[r];
        }
    }
    __syncthreads();

    float mu[4], rs[4];
    #pragma unroll
    for (int r = 0; r < 4; r++) {
        int row = quad * 4 + r;
        float t1 = ssum[row][0] + ssum[row][1] + ssum[row][2] + ssum[row][3];
        float t2 = ssq [row][0] + ssq [row][1] + ssq [row][2] + ssq [row][3];
        mu[r] = t1 * (1.0f / EE);
        float var = t2 * (1.0f / EE) - mu[r] * mu[r];
        rs[r] = rsqrtf(var + 1e-5f);
    }
    #pragma unroll
    for (int nt = 0; nt < 6; nt++) {
        int n = n0 + nt * 16 + fr;
        float gv = g[n], bev = be[n];
        #pragma unroll
        for (int r = 0; r < 4; r++) {
            float v = (acc[nt][r] - mu[r]) * rs[r] * gv + bev;
            size_t idx = (size_t)(m0 + quad * 4 + r) * EE + n;
            if (outf)  outf[idx] = v;
            if (outbf) outbf[idx] = f2bf(v);
        }
    }
}

// ---------------- MFMA flash attention (q = k = v), causal + exact-zero quirk --------
// Causal pairing (tiles p, 31-p => 33 iters/block) + register double-buffer prefetch
// + NO-MAX softmax: scores are bounded (|s|<~5 -> exp<150, sum<3e5, no overflow);
// softmax is shift-invariant so results match the max-subtracted form to rounding.
// Row-sum kept as per-lane partials, reduced once per phase.
__global__ __launch_bounds__(256, 4) void k_attn(const unsigned short* __restrict__ qbf,
                                                 const unsigned short* __restrict__ qbfT,
                                                 unsigned short* __restrict__ cat)
{
    __shared__ unsigned short Qs[64][72];   // [q][d]
    __shared__ unsigned short Ks[64][72];   // [key][d]
    __shared__ unsigned short Vs[64][72];   // [d][key]
    __shared__ unsigned short Ps[64][72];   // [q][key] (wave-private rows)
    const int p = blockIdx.x;               // 0..15
    const int bh = blockIdx.y;              // 0..23
    const int bb = bh / HH, hh = bh % HH;
    const int tid = threadIdx.x;
    const int w = tid >> 6, lane = tid & 63;
    const int fr = lane & 15;
    const int fc = (lane >> 4) * 8;
    const int prow = w * 16 + (lane >> 4) * 4;
    const unsigned short* qb  = qbf  + (size_t)bh * TT * DD;
    const unsigned short* qtb = qbfT + (size_t)bh * DD * TT;
    const int lr = tid >> 2, lc = (tid & 3) * 16;

    #pragma unroll 1
    for (int ph = 0; ph < 2; ph++) {
        const int tile = ph ? (31 - p) : p;
        const int m0 = tile * 64;

        // prefetch key-tile 0 (overlaps Q staging)
        uint4 kr0, kr1, vr0, vr1;
        {
            const unsigned short* kp = qb + (size_t)lr * DD + lc;
            kr0 = *(const uint4*)(kp);
            kr1 = *(const uint4*)(kp + 8);
            const unsigned short* vp = qtb + (size_t)lr * TT + lc;
            vr0 = *(const uint4*)(vp);
            vr1 = *(const uint4*)(vp + 8);
        }

        __syncthreads();   // previous-phase reads done before Qs overwrite
        {
            const unsigned short* qp = qb + (size_t)(m0 + lr) * DD + lc;
            *(uint4*)&Qs[lr][lc]     = *(const uint4*)(qp);
            *(uint4*)&Qs[lr][lc + 8] = *(const uint4*)(qp + 8);
        }
        __syncthreads();
        const bf16x8 qA0 = *(const bf16x8*)&Qs[w * 16 + fr][fc];
        const bf16x8 qA1 = *(const bf16x8*)&Qs[w * 16 + fr][fc + 32];

        f32x4 accO[4];
        #pragma unroll
        for (int dt = 0; dt < 4; dt++) accO[dt] = (f32x4){0.f, 0.f, 0.f, 0.f};
        float ls[4] = {0.f, 0.f, 0.f, 0.f};
        const int rowbase = m0 + prow;

        for (int kt = 0; kt <= tile; kt++) {
            const int s0 = kt * 64;
            __syncthreads();   // prev iteration's LDS reads complete
            *(uint4*)&Ks[lr][lc]     = kr0;
            *(uint4*)&Ks[lr][lc + 8] = kr1;
            *(uint4*)&Vs[lr][lc]     = vr0;
            *(uint4*)&Vs[lr][lc + 8] = vr1;
            if (kt < tile) {
                const unsigned short* kp = qb + (size_t)(s0 + 64 + lr) * DD + lc;
                kr0 = *(const uint4*)(kp);
                kr1 = *(const uint4*)(kp + 8);
                const unsigned short* vp = qtb + (size_t)lr * TT + s0 + 64 + lc;
                vr0 = *(const uint4*)(vp);
                vr1 = *(const uint4*)(vp + 8);
            }
            __syncthreads();   // staged tile visible

            f32x4 S[4];
            #pragma unroll
            for (int nt = 0; nt < 4; nt++) {
                f32x4 acc = (f32x4){0.f, 0.f, 0.f, 0.f};
                bf16x8 b0 = *(const bf16x8*)&Ks[nt * 16 + fr][fc];
                acc = __builtin_amdgcn_mfma_f32_16x16x32_bf16(qA0, b0, acc, 0, 0, 0);
                bf16x8 b1 = *(const bf16x8*)&Ks[nt * 16 + fr][fc + 32];
                acc = __builtin_amdgcn_mfma_f32_16x16x32_bf16(qA1, b1, acc, 0, 0, 0);
                S[nt] = acc;
            }

            // mask (scale -> tril-zero -> zero==-inf quirk) -> p = exp(s)
            #pragma unroll
            for (int nt = 0; nt < 4; nt++) {
                int jg = s0 + nt * 16 + fr;
                #pragma unroll
                for (int r = 0; r < 4; r++) {
                    float v = S[nt][r] * 0.125f;
                    float pv = (jg <= rowbase + r && v != 0.0f) ? __expf(v) : 0.0f;
                    ls[r] += pv;
                    Ps[prow + r][nt * 16 + fr] = f2bf(pv);
                }
            }

            bf16x8 pA0 = *(const bf16x8*)&Ps[w * 16 + fr][fc];
            bf16x8 pA1 = *(const bf16x8*)&Ps[w * 16 + fr][fc + 32];
            #pragma unroll
            for (int dt = 0; dt < 4; dt++) {
                bf16x8 v0 = *(const bf16x8*)&Vs[dt * 16 + fr][fc];
                accO[dt] = __builtin_amdgcn_mfma_f32_16x16x32_bf16(pA0, v0, accO[dt], 0, 0, 0);
                bf16x8 v1 = *(const bf16x8*)&Vs[dt * 16 + fr][fc + 32];
                accO[dt] = __builtin_amdgcn_mfma_f32_16x16x32_bf16(pA1, v1, accO[dt], 0, 0, 0);
            }
        }

        // one-time row-sum reduction + normalize + write [B,T,E] bf16
        #pragma unroll
        for (int r = 0; r < 4; r++) {
            #pragma unroll
            for (int o = 1; o < 16; o <<= 1) ls[r] += __shfl_xor(ls[r], o, 64);
        }
        #pragma unroll
        for (int dt = 0; dt < 4; dt++) {
            #pragma unroll
            for (int r = 0; r < 4; r++) {
                int t = rowbase + r;
                cat[((size_t)bb * TT + t) * EE + hh * DD + dt * 16 + fr] =
                    f2bf(accO[dt][r] / ls[r]);
            }
        }
    }
}

extern "C" void kernel_launch(void* const* d_in, const int* in_sizes, int n_in,
                              void* d_out, int out_size, void* d_ws, size_t ws_size,
                              hipStream_t stream) {
    (void)in_sizes; (void)n_in; (void)out_size; (void)ws_size;
    const float* x   = (const float*)d_in[0];
    const float* Wq  = (const float*)d_in[1];
    const float* Wo  = (const float*)d_in[2];
    const float* bo  = (const float*)d_in[3];
    const float* W1  = (const float*)d_in[4];
    const float* b1  = (const float*)d_in[5];
    const float* W2  = (const float*)d_in[6];
    const float* b2  = (const float*)d_in[7];
    const float* g1  = (const float*)d_in[8];
    const float* be1 = (const float*)d_in[9];
    const float* g2  = (const float*)d_in[10];
    const float* be2 = (const float*)d_in[11];
    float* out = (float*)d_out;

    float* ws = (float*)d_ws;
    const size_t SZ = (size_t)MM * EE;    // 3,145,728 elems / region (12.6 MB fp32)
    float* S0 = ws;                        // x1 fp32 (post-LN1)
    float* S1 = ws + SZ;                   // qbf + qbfT (bf16, fills region exactly)
    float* S2 = ws + 2 * SZ;               // catb (bf16), later h1b (bf16)
    float* S3 = ws + 3 * SZ;               // x1bf + weight bf16 copies

    unsigned short* qbf  = (unsigned short*)S1;
    unsigned short* qbfT = qbf + (size_t)BB * HH * TT * DD;   // AFTER all of qbf (R7 bug!)
    unsigned short* catb = (unsigned short*)S2;
    unsigned short* h1b  = (unsigned short*)S2;               // reuse after catb consumed
    unsigned short* x1bf = (unsigned short*)S3;
    unsigned short* wqb  = x1bf + SZ;
    unsigned short* wob  = wqb + (size_t)EE * EE;
    unsigned short* w1b  = wob + (size_t)EE * EE;
    unsigned short* w2b  = w1b + (size_t)EE * EE;

    k_cvt<<<dim3(4 * 144), dim3(256), 0, stream>>>(Wq, Wo, W1, W2, wqb, wob, w1b, w2b);
    k_qgemm<<<dim3(MM / 16, 2), dim3(256), 0, stream>>>(x, wqb, qbf, qbfT);
    k_attn<<<dim3(16, BB * HH), dim3(256), 0, stream>>>(qbf, qbfT, catb);
    // proj + bo + residual(x) + LN1 -> x1 fp32 (S0) + x1 bf16 (S3)
    k_pln<<<dim3(MM / 16), dim3(256), 0, stream>>>(catb, wob, bo, x, g1, be1, S0, x1bf);
    // FFN1: relu(x1 @ W1^T + b1) -> h1 bf16 (S2; catb already consumed)
    k_mgemm<<<dim3(MM / 16, 2), dim3(256), 0, stream>>>(x1bf, w1b, b1, h1b);
    // FFN2 + b2 + residual(x1) + LN2 -> final out fp32 (d_out)
    k_pln<<<dim3(MM / 16), dim3(256), 0, stream>>>(h1b, w2b, b2, S0, g2, be2, out, nullptr);
}

// Round 10
// 217.888 us; speedup vs baseline: 3.2519x; 1.0736x over previous
//
#include <hip/hip_runtime.h>
#include <math.h>

#define BB 4
#define TT 2048
#define EE 384
#define HH 6
#define DD 64
#define MM (BB*TT)   // 8192 tokens

typedef __attribute__((ext_vector_type(8))) short bf16x8;
typedef __attribute__((ext_vector_type(4))) float f32x4;

__device__ __forceinline__ unsigned short f2bf(float f) {
    unsigned int u = __float_as_uint(f);
    u = (u + 0x7FFFu + ((u >> 16) & 1u)) >> 16;   // RNE
    return (unsigned short)u;
}
__device__ __forceinline__ unsigned int pk2(float a, float b) {
    return (unsigned int)f2bf(a) | ((unsigned int)f2bf(b) << 16);
}

// ---------------- fp32 -> bf16 conversion: weights only (4 x 144 blocks) -------------
__global__ __launch_bounds__(256) void k_cvt(const float* __restrict__ wq,
                                             const float* __restrict__ wo,
                                             const float* __restrict__ w1,
                                             const float* __restrict__ w2,
                                             unsigned short* __restrict__ wqb,
                                             unsigned short* __restrict__ wob,
                                             unsigned short* __restrict__ w1b,
                                             unsigned short* __restrict__ w2b)
{
    int wi = blockIdx.x / 144, off = (blockIdx.x % 144) * 256;
    const float* s4[4] = {wq, wo, w1, w2};
    unsigned short* d4[4] = {wqb, wob, w1b, w2b};
    const float* src = s4[wi]; unsigned short* dst = d4[wi];
    int i = off + threadIdx.x;
    float4 v = ((const float4*)src)[i];
    uint2 o; o.x = pk2(v.x, v.y); o.y = pk2(v.z, v.w);
    ((uint2*)dst)[i] = o;
}

// ---------------- q-GEMM: A fp32 (packed in-register), writes qbf[b,h,t,d] bf16 ------
// Block 16m x 192n, 4 waves x 48n (3 acc tiles), grid (512,2) => 4 blocks/CU.
// (qbfT scatter removed -- the transpose is k_prep's coalesced job now.)
__global__ __launch_bounds__(256, 4) void k_qgemm(const float* __restrict__ A,
                                                  const unsigned short* __restrict__ W,
                                                  unsigned short* __restrict__ qbf)
{
    const int tid = threadIdx.x;
    const int w = tid >> 6, lane = tid & 63;
    const int fr = lane & 15, quad = lane >> 4;
    const int m0 = blockIdx.x * 16;
    const int n0 = blockIdx.y * 192 + w * 48;
    const float* Ap = A + (size_t)(m0 + fr) * EE + quad * 8;
    const unsigned short* Wp = W + (size_t)(n0 + fr) * EE + quad * 8;

    f32x4 acc[3];
    #pragma unroll
    for (int nt = 0; nt < 3; nt++) acc[nt] = (f32x4){0.f, 0.f, 0.f, 0.f};

    #pragma unroll
    for (int k0 = 0; k0 < 12; k0++) {
        float4 a0 = *(const float4*)(Ap + k0 * 32);
        float4 a1 = *(const float4*)(Ap + k0 * 32 + 4);
        unsigned int ap[4];
        ap[0] = pk2(a0.x, a0.y); ap[1] = pk2(a0.z, a0.w);
        ap[2] = pk2(a1.x, a1.y); ap[3] = pk2(a1.z, a1.w);
        bf16x8 a = *(const bf16x8*)ap;
        #pragma unroll
        for (int nt = 0; nt < 3; nt++) {
            bf16x8 b = *(const bf16x8*)(Wp + (size_t)nt * 16 * EE + k0 * 32);
            acc[nt] = __builtin_amdgcn_mfma_f32_16x16x32_bf16(a, b, acc[nt], 0, 0, 0);
        }
    }

    const int mrow = m0 + quad * 4;
    #pragma unroll
    for (int nt = 0; nt < 3; nt++) {
        int n = n0 + nt * 16 + fr;
        int h = n >> 6, d = n & 63;
        #pragma unroll
        for (int r = 0; r < 4; r++) {
            int m = mrow + r;
            int b = m >> 11, t = m & 2047;
            qbf[((size_t)(b * HH + h) * TT + t) * DD + d] = f2bf(acc[nt][r]);
        }
    }
}

// ---------------- transpose qbf[b,h,t,d] -> qbfT[b,h,d,t] (bf16, coalesced) ----------
__global__ __launch_bounds__(256) void k_prep(const unsigned short* __restrict__ qbf,
                                              unsigned short* __restrict__ qbfT)
{
    __shared__ unsigned short Ls[64][72];
    const int bh = blockIdx.y;
    const int t0 = blockIdx.x * 64;
    const unsigned short* src = qbf + ((size_t)bh * TT + t0) * DD;
    {
        int r = threadIdx.x >> 2, c = (threadIdx.x & 3) * 16;
        const unsigned short* p = src + (size_t)r * DD + c;
        *(uint4*)&Ls[r][c]     = *(const uint4*)(p);
        *(uint4*)&Ls[r][c + 8] = *(const uint4*)(p + 8);
    }
    __syncthreads();
    {
        int d = threadIdx.x >> 2, tc = (threadIdx.x & 3) * 16;
        unsigned short tmp[16];
        #pragma unroll
        for (int i = 0; i < 16; i++) tmp[i] = Ls[tc + i][d];
        unsigned short* dst = qbfT + ((size_t)bh * DD + d) * TT + t0 + tc;
        *(uint4*)(dst)     = *(const uint4*)&tmp[0];
        *(uint4*)(dst + 8) = *(const uint4*)&tmp[8];
    }
}

// ---------------- MFMA flash attention: 32-row q-tiles, q-half x key-half waves ------
// Pair (p, 63-p) of 32-row tiles => exactly 33 key-tile iterations/block; 768 blocks
// (3/CU, 2x R9's parallelism). Wave (qhalf, keyhalf) computes partial accO/ls over its
// 32-key half -- exact linear partials under no-max softmax, combined once per phase
// via LDS. Register double-buffer K/V prefetch as in R9.
__global__ __launch_bounds__(256, 4) void k_attn(const unsigned short* __restrict__ qbf,
                                                 const unsigned short* __restrict__ qbfT,
                                                 unsigned short* __restrict__ cat)
{
    __shared__ unsigned short Qs[32][72];   // [q][d]
    __shared__ unsigned short Ks[64][72];   // [key][d]
    __shared__ unsigned short Vs[64][72];   // [d][key]
    __shared__ unsigned short Ps[32][72];   // [q][key] (wave-private row x col slices)
    __shared__ float Oc[32][68];            // key-half-1 partial O
    __shared__ float lsc[32];               // key-half-1 partial row sums
    const int p = blockIdx.x;               // 0..31
    const int bh = blockIdx.y;              // 0..23
    const int bb = bh / HH, hh = bh % HH;
    const int tid = threadIdx.x;
    const int w = tid >> 6, lane = tid & 63;
    const int qhalf = w & 1, keyhalf = w >> 1;
    const int fr = lane & 15, quad = lane >> 4;
    const int fc = quad * 8;
    const unsigned short* qb  = qbf  + (size_t)bh * TT * DD;
    const unsigned short* qtb = qbfT + (size_t)bh * DD * TT;
    const int lr = tid >> 2, lc = (tid & 3) * 16;     // K/V loader: 64 rows x 16
    const int qr = tid >> 3, qc = (tid & 7) * 8;      // Q loader: 32 rows x 8

    #pragma unroll 1
    for (int ph = 0; ph < 2; ph++) {
        const int tile = ph ? (63 - p) : p;           // 32-row tile index 0..63
        const int m0 = tile * 32;
        const int nkt = (tile >> 1) + 1;              // number of 64-wide key tiles

        // prefetch key-tile 0 (overlaps Q staging)
        uint4 kr0, kr1, vr0, vr1;
        {
            const unsigned short* kp = qb + (size_t)lr * DD + lc;
            kr0 = *(const uint4*)(kp);
            kr1 = *(const uint4*)(kp + 8);
            const unsigned short* vp = qtb + (size_t)lr * TT + lc;
            vr0 = *(const uint4*)(vp);
            vr1 = *(const uint4*)(vp + 8);
        }

        __syncthreads();   // previous-phase reads done before Qs overwrite
        {
            const unsigned short* qp = qb + (size_t)(m0 + qr) * DD + qc;
            *(uint4*)&Qs[qr][qc] = *(const uint4*)(qp);
        }
        __syncthreads();
        const bf16x8 qA0 = *(const bf16x8*)&Qs[qhalf * 16 + fr][fc];
        const bf16x8 qA1 = *(const bf16x8*)&Qs[qhalf * 16 + fr][fc + 32];

        f32x4 accO[4];
        #pragma unroll
        for (int dt = 0; dt < 4; dt++) accO[dt] = (f32x4){0.f, 0.f, 0.f, 0.f};
        float ls[4] = {0.f, 0.f, 0.f, 0.f};
        const int rowbase = m0 + qhalf * 16 + quad * 4;
        const int prow = qhalf * 16 + quad * 4;

        for (int kt = 0; kt < nkt; kt++) {
            const int s0 = kt * 64;
            __syncthreads();   // prev iteration's LDS reads complete
            *(uint4*)&Ks[lr][lc]     = kr0;
            *(uint4*)&Ks[lr][lc + 8] = kr1;
            *(uint4*)&Vs[lr][lc]     = vr0;
            *(uint4*)&Vs[lr][lc + 8] = vr1;
            if (kt < nkt - 1) {
                const unsigned short* kp = qb + (size_t)(s0 + 64 + lr) * DD + lc;
                kr0 = *(const uint4*)(kp);
                kr1 = *(const uint4*)(kp + 8);
                const unsigned short* vp = qtb + (size_t)lr * TT + s0 + 64 + lc;
                vr0 = *(const uint4*)(vp);
                vr1 = *(const uint4*)(vp + 8);
            }
            __syncthreads();   // staged tile visible

            // ---- S (16q x 32key slice): 2 n-tiles x 2 k-steps ----
            f32x4 S[2];
            #pragma unroll
            for (int nt = 0; nt < 2; nt++) {
                f32x4 acc = (f32x4){0.f, 0.f, 0.f, 0.f};
                bf16x8 b0 = *(const bf16x8*)&Ks[keyhalf * 32 + nt * 16 + fr][fc];
                acc = __builtin_amdgcn_mfma_f32_16x16x32_bf16(qA0, b0, acc, 0, 0, 0);
                bf16x8 b1 = *(const bf16x8*)&Ks[keyhalf * 32 + nt * 16 + fr][fc + 32];
                acc = __builtin_amdgcn_mfma_f32_16x16x32_bf16(qA1, b1, acc, 0, 0, 0);
                S[nt] = acc;
            }

            // ---- mask (scale -> tril-zero -> zero==-inf quirk) -> p = exp(s) ----
            #pragma unroll
            for (int nt = 0; nt < 2; nt++) {
                int jg = s0 + keyhalf * 32 + nt * 16 + fr;
                #pragma unroll
                for (int r = 0; r < 4; r++) {
                    float v = S[nt][r] * 0.125f;
                    float pv = (jg <= rowbase + r && v != 0.0f) ? __expf(v) : 0.0f;
                    ls[r] += pv;
                    Ps[prow + r][keyhalf * 32 + nt * 16 + fr] = f2bf(pv);
                }
            }

            // ---- O += P . V over this wave's 32-key half (K=32: 1 MFMA per dt) ----
            bf16x8 pA = *(const bf16x8*)&Ps[qhalf * 16 + fr][keyhalf * 32 + fc];
            #pragma unroll
            for (int dt = 0; dt < 4; dt++) {
                bf16x8 v0 = *(const bf16x8*)&Vs[dt * 16 + fr][keyhalf * 32 + fc];
                accO[dt] = __builtin_amdgcn_mfma_f32_16x16x32_bf16(pA, v0, accO[dt], 0, 0, 0);
            }
        }

        // ---- reduce ls over the 16 fr-lanes, combine key-halves, write out ----
        #pragma unroll
        for (int r = 0; r < 4; r++) {
            #pragma unroll
            for (int o = 1; o < 16; o <<= 1) ls[r] += __shfl_xor(ls[r], o, 64);
        }
        if (keyhalf == 1) {
            #pragma unroll
            for (int dt = 0; dt < 4; dt++)
                #pragma unroll
                for (int r = 0; r < 4; r++)
                    Oc[prow + r][dt * 16 + fr] = accO[dt][r];
            if (fr == 0) {
                #pragma unroll
                for (int r = 0; r < 4; r++) lsc[prow + r] = ls[r];
            }
        }
        __syncthreads();
        if (keyhalf == 0) {
            float lt[4];
            #pragma unroll
            for (int r = 0; r < 4; r++) lt[r] = ls[r] + lsc[prow + r];
            #pragma unroll
            for (int dt = 0; dt < 4; dt++) {
                #pragma unroll
                for (int r = 0; r < 4; r++) {
                    float o = accO[dt][r] + Oc[prow + r][dt * 16 + fr];
                    int t = rowbase + r;
                    cat[((size_t)bb * TT + t) * EE + hh * DD + dt * 16 + fr] =
                        f2bf(o / lt[r]);
                }
            }
        }
    }
}

// ---------------- fused proj+LN1 + FFN1 + FFN2+LN2: entire post-attention path -------
// Block = 16 rows x full N=384 (4 waves x 96n). x1 and h1 round-trip through LDS only;
// the x1 residual for LN2 stays in registers (GEMM1/GEMM3 share the lane->(m,n) map).
__global__ __launch_bounds__(256, 2) void k_ffn(const unsigned short* __restrict__ catb,
                                                const unsigned short* __restrict__ wob,
                                                const float* __restrict__ bo,
                                                const float* __restrict__ x,
                                                const float* __restrict__ g1,
                                                const float* __restrict__ be1,
                                                const unsigned short* __restrict__ w1b,
                                                const float* __restrict__ b1,
                                                const unsigned short* __restrict__ w2b,
                                                const float* __restrict__ b2,
                                                const float* __restrict__ g2,
                                                const float* __restrict__ be2,
                                                float* __restrict__ out)
{
    __shared__ unsigned short X1s[16][392];
    __shared__ unsigned short H1s[16][392];
    __shared__ float ssum[16][4];
    __shared__ float ssq[16][4];
    const int tid = threadIdx.x;
    const int w = tid >> 6, lane = tid & 63;
    const int fr = lane & 15, quad = lane >> 4;
    const int m0 = blockIdx.x * 16;
    const int n0 = w * 96;

    f32x4 acc[6];

    // ================= GEMM1: proj = catb @ Wo^T =================
    {
        const unsigned short* Ap = catb + (size_t)(m0 + fr) * EE + quad * 8;
        const unsigned short* Wp = wob + (size_t)(n0 + fr) * EE + quad * 8;
        #pragma unroll
        for (int nt = 0; nt < 6; nt++) acc[nt] = (f32x4){0.f, 0.f, 0.f, 0.f};
        #pragma unroll
        for (int k0 = 0; k0 < 12; k0++) {
            bf16x8 a = *(const bf16x8*)(Ap + k0 * 32);
            #pragma unroll
            for (int nt = 0; nt < 6; nt++) {
                bf16x8 b = *(const bf16x8*)(Wp + (size_t)nt * 16 * EE + k0 * 32);
                acc[nt] = __builtin_amdgcn_mfma_f32_16x16x32_bf16(a, b, acc[nt], 0, 0, 0);
            }
        }
    }
    // + bo + resid(x) -> LN1 stats
    float s1[4] = {0.f, 0.f, 0.f, 0.f}, s2[4] = {0.f, 0.f, 0.f, 0.f};
    #pragma unroll
    for (int nt = 0; nt < 6; nt++) {
        int n = n0 + nt * 16 + fr;
        float bv = bo[n];
        #pragma unroll
        for (int r = 0; r < 4; r++) {
            float v = acc[nt][r] + bv + x[(size_t)(m0 + quad * 4 + r) * EE + n];
            acc[nt][r] = v;
            s1[r] += v;
            s2[r] += v * v;
        }
    }
    #pragma unroll
    for (int r = 0; r < 4; r++) {
        #pragma unroll
        for (int o = 1; o < 16; o <<= 1) {
            s1[r] += __shfl_xor(s1[r], o, 64);
            s2[r] += __shfl_xor(s2[r], o, 64);
        }
    }
    if (fr == 0) {
        #pragma unroll
        for (int r = 0; r < 4; r++) { ssum[quad * 4 + r][w] = s1[r]; ssq[quad * 4 + r][w] = s2[r]; }
    }
    __syncthreads();
    float x1v[6][4];   // x1 for this lane's (nt, r) positions -- LN2 residual later
    {
        float mu[4], rs[4];
        #pragma unroll
        for (int r = 0; r < 4; r++) {
            int row = quad * 4 + r;
            float t1 = ssum[row][0] + ssum[row][1] + ssum[row][2] + ssum[row][3];
            float t2 = ssq[row][0] + ssq[row][1] + ssq[row][2] + ssq[row][3];
            mu[r] = t1 * (1.0f / EE);
            float var = t2 * (1.0f / EE) - mu[r] * mu[r];
            rs[r] = rsqrtf(var + 1e-5f);
        }
        #pragma unroll
        for (int nt = 0; nt < 6; nt++) {
            int n = n0 + nt * 16 + fr;
            float gv = g1[n], bev = be1[n];
            #pragma unroll
            for (int r = 0; r < 4; r++) {
                float v = (acc[nt][r] - mu[r]) * rs[r] * gv + bev;
                x1v[nt][r] = v;
                X1s[quad * 4 + r][n] = f2bf(v);
            }
        }
    }
    __syncthreads();

    // ================= GEMM2: h1 = relu(x1 @ W1^T + b1) =================
    {
        const unsigned short* Wp = w1b + (size_t)(n0 + fr) * EE + quad * 8;
        #pragma unroll
        for (int nt = 0; nt < 6; nt++) acc[nt] = (f32x4){0.f, 0.f, 0.f, 0.f};
        #pragma unroll
        for (int k0 = 0; k0 < 12; k0++) {
            bf16x8 a = *(const bf16x8*)&X1s[fr][k0 * 32 + quad * 8];
            #pragma unroll
            for (int nt = 0; nt < 6; nt++) {
                bf16x8 b = *(const bf16x8*)(Wp + (size_t)nt * 16 * EE + k0 * 32);
                acc[nt] = __builtin_amdgcn_mfma_f32_16x16x32_bf16(a, b, acc[nt], 0, 0, 0);
            }
        }
        #pragma unroll
        for (int nt = 0; nt < 6; nt++) {
            int n = n0 + nt * 16 + fr;
            float bv = b1[n];
            #pragma unroll
            for (int r = 0; r < 4; r++)
                H1s[quad * 4 + r][n] = f2bf(fmaxf(acc[nt][r] + bv, 0.0f));
        }
    }
    __syncthreads();

    // ================= GEMM3: ff = h1 @ W2^T + b2; LN2(x1 + ff) -> out =================
    {
        const unsigned short* Wp = w2b + (size_t)(n0 + fr) * EE + quad * 8;
        #pragma unroll
        for (int nt = 0; nt < 6; nt++) acc[nt] = (f32x4){0.f, 0.f, 0.f, 0.f};
        #pragma unroll
        for (int k0 = 0; k0 < 12; k0++) {
            bf16x8 a = *(const bf16x8*)&H1s[fr][k0 * 32 + quad * 8];
            #pragma unroll
            for (int nt = 0; nt < 6; nt++) {
                bf16x8 b = *(const bf16x8*)(Wp + (size_t)nt * 16 * EE + k0 * 32);
                acc[nt] = __builtin_amdgcn_mfma_f32_16x16x32_bf16(a, b, acc[nt], 0, 0, 0);
            }
        }
    }
    float t1[4] = {0.f, 0.f, 0.f, 0.f}, t2[4] = {0.f, 0.f, 0.f, 0.f};
    #pragma unroll
    for (int nt = 0; nt < 6; nt++) {
        int n = n0 + nt * 16 + fr;
        float bv = b2[n];
        #pragma unroll
        for (int r = 0; r < 4; r++) {
            float v = acc[nt][r] + bv + x1v[nt][r];
            acc[nt][r] = v;
            t1[r] += v;
            t2[r] += v * v;
        }
    }
    #pragma unroll
    for (int r = 0; r < 4; r++) {
        #pragma unroll
        for (int o = 1; o < 16; o <<= 1) {
            t1[r] += __shfl_xor(t1[r], o, 64);
            t2[r] += __shfl_xor(t2[r], o, 64);
        }
    }
    if (fr == 0) {
        #pragma unroll
        for (int r = 0; r < 4; r++) { ssum[quad * 4 + r][w] = t1[r]; ssq[quad * 4 + r][w] = t2[r]; }
    }
    __syncthreads();
    {
        float mu[4], rs[4];
        #pragma unroll
        for (int r = 0; r < 4; r++) {
            int row = quad * 4 + r;
            float u1 = ssum[row][0] + ssum[row][1] + ssum[row][2] + ssum[row][3];
            float u2 = ssq[row][0] + ssq[row][1] + ssq[row][2] + ssq[row][3];
            mu[r] = u1 * (1.0f / EE);
            float var = u2 * (1.0f / EE) - mu[r] * mu[r];
            rs[r] = rsqrtf(var + 1e-5f);
        }
        #pragma unroll
        for (int nt = 0; nt < 6; nt++) {
            int n = n0 + nt * 16 + fr;
            float gv = g2[n], bev = be2[n];
            #pragma unroll
            for (int r = 0; r < 4; r++)
                out[(size_t)(m0 + quad * 4 + r) * EE + n] =
                    (acc[nt][r] - mu[r]) * rs[r] * gv + bev;
        }
    }
}

extern "C" void kernel_launch(void* const* d_in, const int* in_sizes, int n_in,
                              void* d_out, int out_size, void* d_ws, size_t ws_size,
                              hipStream_t stream) {
    (void)in_sizes; (void)n_in; (void)out_size; (void)ws_size;
    const float* x   = (const float*)d_in[0];
    const float* Wq  = (const float*)d_in[1];
    const float* Wo  = (const float*)d_in[2];
    const float* bo  = (const float*)d_in[3];
    const float* W1  = (const float*)d_in[4];
    const float* b1  = (const float*)d_in[5];
    const float* W2  = (const float*)d_in[6];
    const float* b2  = (const float*)d_in[7];
    const float* g1  = (const float*)d_in[8];
    const float* be1 = (const float*)d_in[9];
    const float* g2  = (const float*)d_in[10];
    const float* be2 = (const float*)d_in[11];
    float* out = (float*)d_out;

    float* ws = (float*)d_ws;
    const size_t SZ = (size_t)MM * EE;    // 3,145,728 elems / region (12.6 MB fp32)
    float* S1 = ws + SZ;                   // qbf + qbfT (bf16, fills region exactly)
    float* S2 = ws + 2 * SZ;               // catb (bf16)
    float* S3 = ws + 3 * SZ;               // weight bf16 copies

    unsigned short* qbf  = (unsigned short*)S1;
    unsigned short* qbfT = qbf + (size_t)BB * HH * TT * DD;   // AFTER all of qbf!
    unsigned short* catb = (unsigned short*)S2;
    unsigned short* wqb  = (unsigned short*)S3;
    unsigned short* wob  = wqb + (size_t)EE * EE;
    unsigned short* w1b  = wob + (size_t)EE * EE;
    unsigned short* w2b  = w1b + (size_t)EE * EE;

    k_cvt<<<dim3(4 * 144), dim3(256), 0, stream>>>(Wq, Wo, W1, W2, wqb, wob, w1b, w2b);
    k_qgemm<<<dim3(MM / 16, 2), dim3(256), 0, stream>>>(x, wqb, qbf);
    k_prep<<<dim3(TT / 64, BB * HH), dim3(256), 0, stream>>>(qbf, qbfT);
    k_attn<<<dim3(32, BB * HH), dim3(256), 0, stream>>>(qbf, qbfT, catb);
    k_ffn<<<dim3(MM / 16), dim3(256), 0, stream>>>(catb, wob, bo, x, g1, be1,
                                                   w1b, b1, w2b, b2, g2, be2, out);
}

// Round 11
// 204.697 us; speedup vs baseline: 3.4615x; 1.0644x over previous
//
#include <hip/hip_runtime.h>
#include <math.h>

#define BB 4
#define TT 2048
#define EE 384
#define HH 6
#define DD 64
#define MM (BB*TT)   // 8192 tokens

typedef __attribute__((ext_vector_type(8))) short bf16x8;
typedef __attribute__((ext_vector_type(4))) float f32x4;

__device__ __forceinline__ unsigned short f2bf(float f) {
    unsigned int u = __float_as_uint(f);
    u = (u + 0x7FFFu + ((u >> 16) & 1u)) >> 16;   // RNE
    return (unsigned short)u;
}
__device__ __forceinline__ float bf2f(unsigned short u) {
    return __uint_as_float(((unsigned int)u) << 16);
}
__device__ __forceinline__ unsigned int pk2(float a, float b) {
    return (unsigned int)f2bf(a) | ((unsigned int)f2bf(b) << 16);
}

// ---------------- fp32 -> bf16 conversion: weights only (4 x 144 blocks) -------------
__global__ __launch_bounds__(256) void k_cvt(const float* __restrict__ wq,
                                             const float* __restrict__ wo,
                                             const float* __restrict__ w1,
                                             const float* __restrict__ w2,
                                             unsigned short* __restrict__ wqb,
                                             unsigned short* __restrict__ wob,
                                             unsigned short* __restrict__ w1b,
                                             unsigned short* __restrict__ w2b)
{
    int wi = blockIdx.x / 144, off = (blockIdx.x % 144) * 256;
    const float* s4[4] = {wq, wo, w1, w2};
    unsigned short* d4[4] = {wqb, wob, w1b, w2b};
    const float* src = s4[wi]; unsigned short* dst = d4[wi];
    int i = off + threadIdx.x;
    float4 v = ((const float4*)src)[i];
    uint2 o; o.x = pk2(v.x, v.y); o.y = pk2(v.z, v.w);
    ((uint2*)dst)[i] = o;
}

// ---------------- q-GEMM: A fp32 (packed in-register), writes qbf[b,h,t,d] bf16 ------
__global__ __launch_bounds__(256, 4) void k_qgemm(const float* __restrict__ A,
                                                  const unsigned short* __restrict__ W,
                                                  unsigned short* __restrict__ qbf)
{
    const int tid = threadIdx.x;
    const int w = tid >> 6, lane = tid & 63;
    const int fr = lane & 15, quad = lane >> 4;
    const int m0 = blockIdx.x * 16;
    const int n0 = blockIdx.y * 192 + w * 48;
    const float* Ap = A + (size_t)(m0 + fr) * EE + quad * 8;
    const unsigned short* Wp = W + (size_t)(n0 + fr) * EE + quad * 8;

    f32x4 acc[3];
    #pragma unroll
    for (int nt = 0; nt < 3; nt++) acc[nt] = (f32x4){0.f, 0.f, 0.f, 0.f};

    #pragma unroll
    for (int k0 = 0; k0 < 12; k0++) {
        float4 a0 = *(const float4*)(Ap + k0 * 32);
        float4 a1 = *(const float4*)(Ap + k0 * 32 + 4);
        unsigned int ap[4];
        ap[0] = pk2(a0.x, a0.y); ap[1] = pk2(a0.z, a0.w);
        ap[2] = pk2(a1.x, a1.y); ap[3] = pk2(a1.z, a1.w);
        bf16x8 a = *(const bf16x8*)ap;
        #pragma unroll
        for (int nt = 0; nt < 3; nt++) {
            bf16x8 b = *(const bf16x8*)(Wp + (size_t)nt * 16 * EE + k0 * 32);
            acc[nt] = __builtin_amdgcn_mfma_f32_16x16x32_bf16(a, b, acc[nt], 0, 0, 0);
        }
    }

    const int mrow = m0 + quad * 4;
    #pragma unroll
    for (int nt = 0; nt < 3; nt++) {
        int n = n0 + nt * 16 + fr;
        int h = n >> 6, d = n & 63;
        #pragma unroll
        for (int r = 0; r < 4; r++) {
            int m = mrow + r;
            int b = m >> 11, t = m & 2047;
            qbf[((size_t)(b * HH + h) * TT + t) * DD + d] = f2bf(acc[nt][r]);
        }
    }
}

// ---------------- transpose qbf[b,h,t,d] -> qbfT[b,h,d,t] (bf16, coalesced) ----------
__global__ __launch_bounds__(256) void k_prep(const unsigned short* __restrict__ qbf,
                                              unsigned short* __restrict__ qbfT)
{
    __shared__ unsigned short Ls[64][72];
    const int bh = blockIdx.y;
    const int t0 = blockIdx.x * 64;
    const unsigned short* src = qbf + ((size_t)bh * TT + t0) * DD;
    {
        int r = threadIdx.x >> 2, c = (threadIdx.x & 3) * 16;
        const unsigned short* p = src + (size_t)r * DD + c;
        *(uint4*)&Ls[r][c]     = *(const uint4*)(p);
        *(uint4*)&Ls[r][c + 8] = *(const uint4*)(p + 8);
    }
    __syncthreads();
    {
        int d = threadIdx.x >> 2, tc = (threadIdx.x & 3) * 16;
        unsigned short tmp[16];
        #pragma unroll
        for (int i = 0; i < 16; i++) tmp[i] = Ls[tc + i][d];
        unsigned short* dst = qbfT + ((size_t)bh * DD + d) * TT + t0 + tc;
        *(uint4*)(dst)     = *(const uint4*)&tmp[0];
        *(uint4*)(dst + 8) = *(const uint4*)&tmp[8];
    }
}

// ---------------- MFMA flash attention: 32-row q-tiles, q-half x key-half waves ------
// (unchanged from R10)
__global__ __launch_bounds__(256, 4) void k_attn(const unsigned short* __restrict__ qbf,
                                                 const unsigned short* __restrict__ qbfT,
                                                 unsigned short* __restrict__ cat)
{
    __shared__ unsigned short Qs[32][72];
    __shared__ unsigned short Ks[64][72];
    __shared__ unsigned short Vs[64][72];
    __shared__ unsigned short Ps[32][72];
    __shared__ float Oc[32][68];
    __shared__ float lsc[32];
    const int p = blockIdx.x;
    const int bh = blockIdx.y;
    const int bb = bh / HH, hh = bh % HH;
    const int tid = threadIdx.x;
    const int w = tid >> 6, lane = tid & 63;
    const int qhalf = w & 1, keyhalf = w >> 1;
    const int fr = lane & 15, quad = lane >> 4;
    const int fc = quad * 8;
    const unsigned short* qb  = qbf  + (size_t)bh * TT * DD;
    const unsigned short* qtb = qbfT + (size_t)bh * DD * TT;
    const int lr = tid >> 2, lc = (tid & 3) * 16;
    const int qr = tid >> 3, qc = (tid & 7) * 8;

    #pragma unroll 1
    for (int ph = 0; ph < 2; ph++) {
        const int tile = ph ? (63 - p) : p;
        const int m0 = tile * 32;
        const int nkt = (tile >> 1) + 1;

        uint4 kr0, kr1, vr0, vr1;
        {
            const unsigned short* kp = qb + (size_t)lr * DD + lc;
            kr0 = *(const uint4*)(kp);
            kr1 = *(const uint4*)(kp + 8);
            const unsigned short* vp = qtb + (size_t)lr * TT + lc;
            vr0 = *(const uint4*)(vp);
            vr1 = *(const uint4*)(vp + 8);
        }

        __syncthreads();
        {
            const unsigned short* qp = qb + (size_t)(m0 + qr) * DD + qc;
            *(uint4*)&Qs[qr][qc] = *(const uint4*)(qp);
        }
        __syncthreads();
        const bf16x8 qA0 = *(const bf16x8*)&Qs[qhalf * 16 + fr][fc];
        const bf16x8 qA1 = *(const bf16x8*)&Qs[qhalf * 16 + fr][fc + 32];

        f32x4 accO[4];
        #pragma unroll
        for (int dt = 0; dt < 4; dt++) accO[dt] = (f32x4){0.f, 0.f, 0.f, 0.f};
        float ls[4] = {0.f, 0.f, 0.f, 0.f};
        const int rowbase = m0 + qhalf * 16 + quad * 4;
        const int prow = qhalf * 16 + quad * 4;

        for (int kt = 0; kt < nkt; kt++) {
            const int s0 = kt * 64;
            __syncthreads();
            *(uint4*)&Ks[lr][lc]     = kr0;
            *(uint4*)&Ks[lr][lc + 8] = kr1;
            *(uint4*)&Vs[lr][lc]     = vr0;
            *(uint4*)&Vs[lr][lc + 8] = vr1;
            if (kt < nkt - 1) {
                const unsigned short* kp = qb + (size_t)(s0 + 64 + lr) * DD + lc;
                kr0 = *(const uint4*)(kp);
                kr1 = *(const uint4*)(kp + 8);
                const unsigned short* vp = qtb + (size_t)lr * TT + s0 + 64 + lc;
                vr0 = *(const uint4*)(vp);
                vr1 = *(const uint4*)(vp + 8);
            }
            __syncthreads();

            f32x4 S[2];
            #pragma unroll
            for (int nt = 0; nt < 2; nt++) {
                f32x4 acc = (f32x4){0.f, 0.f, 0.f, 0.f};
                bf16x8 b0 = *(const bf16x8*)&Ks[keyhalf * 32 + nt * 16 + fr][fc];
                acc = __builtin_amdgcn_mfma_f32_16x16x32_bf16(qA0, b0, acc, 0, 0, 0);
                bf16x8 b1 = *(const bf16x8*)&Ks[keyhalf * 32 + nt * 16 + fr][fc + 32];
                acc = __builtin_amdgcn_mfma_f32_16x16x32_bf16(qA1, b1, acc, 0, 0, 0);
                S[nt] = acc;
            }

            #pragma unroll
            for (int nt = 0; nt < 2; nt++) {
                int jg = s0 + keyhalf * 32 + nt * 16 + fr;
                #pragma unroll
                for (int r = 0; r < 4; r++) {
                    float v = S[nt][r] * 0.125f;
                    float pv = (jg <= rowbase + r && v != 0.0f) ? __expf(v) : 0.0f;
                    ls[r] += pv;
                    Ps[prow + r][keyhalf * 32 + nt * 16 + fr] = f2bf(pv);
                }
            }

            bf16x8 pA = *(const bf16x8*)&Ps[qhalf * 16 + fr][keyhalf * 32 + fc];
            #pragma unroll
            for (int dt = 0; dt < 4; dt++) {
                bf16x8 v0 = *(const bf16x8*)&Vs[dt * 16 + fr][keyhalf * 32 + fc];
                accO[dt] = __builtin_amdgcn_mfma_f32_16x16x32_bf16(pA, v0, accO[dt], 0, 0, 0);
            }
        }

        #pragma unroll
        for (int r = 0; r < 4; r++) {
            #pragma unroll
            for (int o = 1; o < 16; o <<= 1) ls[r] += __shfl_xor(ls[r], o, 64);
        }
        if (keyhalf == 1) {
            #pragma unroll
            for (int dt = 0; dt < 4; dt++)
                #pragma unroll
                for (int r = 0; r < 4; r++)
                    Oc[prow + r][dt * 16 + fr] = accO[dt][r];
            if (fr == 0) {
                #pragma unroll
                for (int r = 0; r < 4; r++) lsc[prow + r] = ls[r];
            }
        }
        __syncthreads();
        if (keyhalf == 0) {
            float lt[4];
            #pragma unroll
            for (int r = 0; r < 4; r++) lt[r] = ls[r] + lsc[prow + r];
            #pragma unroll
            for (int dt = 0; dt < 4; dt++) {
                #pragma unroll
                for (int r = 0; r < 4; r++) {
                    float o = accO[dt][r] + Oc[prow + r][dt * 16 + fr];
                    int t = rowbase + r;
                    cat[((size_t)bb * TT + t) * EE + hh * DD + dt * 16 + fr] =
                        f2bf(o / lt[r]);
                }
            }
        }
    }
}

// ---------------- fused proj+LN1 + FFN1 + FFN2+LN2 -----------------------------------
// 32 rows/block (2 m-tiles/wave): each b-frag feeds 2 MFMAs (2x arithmetic intensity,
// half the L2 weight traffic) + manual b-frag double-buffer so next k-step's weight
// loads issue before this k-step's MFMAs (compiler wasn't prefetching: VGPR=72).
// x1 residual for LN2 re-read from X1s (bf16) to free registers for the prefetch.
__global__ __launch_bounds__(256, 2) void k_ffn(const unsigned short* __restrict__ catb,
                                                const unsigned short* __restrict__ wob,
                                                const float* __restrict__ bo,
                                                const float* __restrict__ x,
                                                const float* __restrict__ g1,
                                                const float* __restrict__ be1,
                                                const unsigned short* __restrict__ w1b,
                                                const float* __restrict__ b1,
                                                const unsigned short* __restrict__ w2b,
                                                const float* __restrict__ b2,
                                                const float* __restrict__ g2,
                                                const float* __restrict__ be2,
                                                float* __restrict__ out)
{
    __shared__ unsigned short X1s[32][392];
    __shared__ unsigned short H1s[32][392];
    __shared__ float ssum[32][4];
    __shared__ float ssq[32][4];
    const int tid = threadIdx.x;
    const int w = tid >> 6, lane = tid & 63;
    const int fr = lane & 15, quad = lane >> 4;
    const int m0 = blockIdx.x * 32;
    const int n0 = w * 96;

    f32x4 acc[2][6];
    bf16x8 bc[6], bn[6];

    // ================= GEMM1: proj = catb @ Wo^T (2 m-tiles) =================
    {
        const unsigned short* Ap0 = catb + (size_t)(m0 + fr) * EE + quad * 8;
        const unsigned short* Ap1 = Ap0 + 16 * EE;
        const unsigned short* Wp = wob + (size_t)(n0 + fr) * EE + quad * 8;
        #pragma unroll
        for (int mt = 0; mt < 2; mt++)
            #pragma unroll
            for (int nt = 0; nt < 6; nt++) acc[mt][nt] = (f32x4){0.f, 0.f, 0.f, 0.f};
        #pragma unroll
        for (int nt = 0; nt < 6; nt++) bc[nt] = *(const bf16x8*)(Wp + (size_t)nt * 16 * EE);
        #pragma unroll
        for (int k0 = 0; k0 < 12; k0++) {
            if (k0 < 11) {
                #pragma unroll
                for (int nt = 0; nt < 6; nt++)
                    bn[nt] = *(const bf16x8*)(Wp + (size_t)nt * 16 * EE + (k0 + 1) * 32);
            }
            bf16x8 a0 = *(const bf16x8*)(Ap0 + k0 * 32);
            bf16x8 a1 = *(const bf16x8*)(Ap1 + k0 * 32);
            #pragma unroll
            for (int nt = 0; nt < 6; nt++) {
                acc[0][nt] = __builtin_amdgcn_mfma_f32_16x16x32_bf16(a0, bc[nt], acc[0][nt], 0, 0, 0);
                acc[1][nt] = __builtin_amdgcn_mfma_f32_16x16x32_bf16(a1, bc[nt], acc[1][nt], 0, 0, 0);
            }
            #pragma unroll
            for (int nt = 0; nt < 6; nt++) bc[nt] = bn[nt];
        }
    }
    // + bo + resid(x) -> LN1 stats (per m-tile)
    {
        float s1[2][4] = {{0.f,0.f,0.f,0.f},{0.f,0.f,0.f,0.f}};
        float s2[2][4] = {{0.f,0.f,0.f,0.f},{0.f,0.f,0.f,0.f}};
        #pragma unroll
        for (int nt = 0; nt < 6; nt++) {
            int n = n0 + nt * 16 + fr;
            float bv = bo[n];
            #pragma unroll
            for (int mt = 0; mt < 2; mt++)
                #pragma unroll
                for (int r = 0; r < 4; r++) {
                    float v = acc[mt][nt][r] + bv
                            + x[(size_t)(m0 + mt * 16 + quad * 4 + r) * EE + n];
                    acc[mt][nt][r] = v;
                    s1[mt][r] += v;
                    s2[mt][r] += v * v;
                }
        }
        #pragma unroll
        for (int mt = 0; mt < 2; mt++)
            #pragma unroll
            for (int r = 0; r < 4; r++) {
                #pragma unroll
                for (int o = 1; o < 16; o <<= 1) {
                    s1[mt][r] += __shfl_xor(s1[mt][r], o, 64);
                    s2[mt][r] += __shfl_xor(s2[mt][r], o, 64);
                }
            }
        if (fr == 0) {
            #pragma unroll
            for (int mt = 0; mt < 2; mt++)
                #pragma unroll
                for (int r = 0; r < 4; r++) {
                    ssum[mt * 16 + quad * 4 + r][w] = s1[mt][r];
                    ssq [mt * 16 + quad * 4 + r][w] = s2[mt][r];
                }
        }
    }
    __syncthreads();
    {
        #pragma unroll
        for (int mt = 0; mt < 2; mt++) {
            float mu[4], rs[4];
            #pragma unroll
            for (int r = 0; r < 4; r++) {
                int row = mt * 16 + quad * 4 + r;
                float t1 = ssum[row][0] + ssum[row][1] + ssum[row][2] + ssum[row][3];
                float t2 = ssq[row][0] + ssq[row][1] + ssq[row][2] + ssq[row][3];
                mu[r] = t1 * (1.0f / EE);
                float var = t2 * (1.0f / EE) - mu[r] * mu[r];
                rs[r] = rsqrtf(var + 1e-5f);
            }
            #pragma unroll
            for (int nt = 0; nt < 6; nt++) {
                int n = n0 + nt * 16 + fr;
                float gv = g1[n], bev = be1[n];
                #pragma unroll
                for (int r = 0; r < 4; r++) {
                    float v = (acc[mt][nt][r] - mu[r]) * rs[r] * gv + bev;
                    X1s[mt * 16 + quad * 4 + r][n] = f2bf(v);
                }
            }
        }
    }
    __syncthreads();

    // ================= GEMM2: h1 = relu(x1 @ W1^T + b1) =================
    {
        const unsigned short* Wp = w1b + (size_t)(n0 + fr) * EE + quad * 8;
        #pragma unroll
        for (int mt = 0; mt < 2; mt++)
            #pragma unroll
            for (int nt = 0; nt < 6; nt++) acc[mt][nt] = (f32x4){0.f, 0.f, 0.f, 0.f};
        #pragma unroll
        for (int nt = 0; nt < 6; nt++) bc[nt] = *(const bf16x8*)(Wp + (size_t)nt * 16 * EE);
        #pragma unroll
        for (int k0 = 0; k0 < 12; k0++) {
            if (k0 < 11) {
                #pragma unroll
                for (int nt = 0; nt < 6; nt++)
                    bn[nt] = *(const bf16x8*)(Wp + (size_t)nt * 16 * EE + (k0 + 1) * 32);
            }
            bf16x8 a0 = *(const bf16x8*)&X1s[fr][k0 * 32 + quad * 8];
            bf16x8 a1 = *(const bf16x8*)&X1s[16 + fr][k0 * 32 + quad * 8];
            #pragma unroll
            for (int nt = 0; nt < 6; nt++) {
                acc[0][nt] = __builtin_amdgcn_mfma_f32_16x16x32_bf16(a0, bc[nt], acc[0][nt], 0, 0, 0);
                acc[1][nt] = __builtin_amdgcn_mfma_f32_16x16x32_bf16(a1, bc[nt], acc[1][nt], 0, 0, 0);
            }
            #pragma unroll
            for (int nt = 0; nt < 6; nt++) bc[nt] = bn[nt];
        }
        #pragma unroll
        for (int nt = 0; nt < 6; nt++) {
            int n = n0 + nt * 16 + fr;
            float bv = b1[n];
            #pragma unroll
            for (int mt = 0; mt < 2; mt++)
                #pragma unroll
                for (int r = 0; r < 4; r++)
                    H1s[mt * 16 + quad * 4 + r][n] = f2bf(fmaxf(acc[mt][nt][r] + bv, 0.0f));
        }
    }
    __syncthreads();

    // ================= GEMM3: ff = h1 @ W2^T + b2; LN2(x1 + ff) -> out =================
    {
        const unsigned short* Wp = w2b + (size_t)(n0 + fr) * EE + quad * 8;
        #pragma unroll
        for (int mt = 0; mt < 2; mt++)
            #pragma unroll
            for (int nt = 0; nt < 6; nt++) acc[mt][nt] = (f32x4){0.f, 0.f, 0.f, 0.f};
        #pragma unroll
        for (int nt = 0; nt < 6; nt++) bc[nt] = *(const bf16x8*)(Wp + (size_t)nt * 16 * EE);
        #pragma unroll
        for (int k0 = 0; k0 < 12; k0++) {
            if (k0 < 11) {
                #pragma unroll
                for (int nt = 0; nt < 6; nt++)
                    bn[nt] = *(const bf16x8*)(Wp + (size_t)nt * 16 * EE + (k0 + 1) * 32);
            }
            bf16x8 a0 = *(const bf16x8*)&H1s[fr][k0 * 32 + quad * 8];
            bf16x8 a1 = *(const bf16x8*)&H1s[16 + fr][k0 * 32 + quad * 8];
            #pragma unroll
            for (int nt = 0; nt < 6; nt++) {
                acc[0][nt] = __builtin_amdgcn_mfma_f32_16x16x32_bf16(a0, bc[nt], acc[0][nt], 0, 0, 0);
                acc[1][nt] = __builtin_amdgcn_mfma_f32_16x16x32_bf16(a1, bc[nt], acc[1][nt], 0, 0, 0);
            }
            #pragma unroll
            for (int nt = 0; nt < 6; nt++) bc[nt] = bn[nt];
        }
    }
    {
        float s1[2][4] = {{0.f,0.f,0.f,0.f},{0.f,0.f,0.f,0.f}};
        float s2[2][4] = {{0.f,0.f,0.f,0.f},{0.f,0.f,0.f,0.f}};
        #pragma unroll
        for (int nt = 0; nt < 6; nt++) {
            int n = n0 + nt * 16 + fr;
            float bv = b2[n];
            #pragma unroll
            for (int mt = 0; mt < 2; mt++)
                #pragma unroll
                for (int r = 0; r < 4; r++) {
                    float v = acc[mt][nt][r] + bv
                            + bf2f(X1s[mt * 16 + quad * 4 + r][n]);   // x1 residual (bf16)
                    acc[mt][nt][r] = v;
                    s1[mt][r] += v;
                    s2[mt][r] += v * v;
                }
        }
        #pragma unroll
        for (int mt = 0; mt < 2; mt++)
            #pragma unroll
            for (int r = 0; r < 4; r++) {
                #pragma unroll
                for (int o = 1; o < 16; o <<= 1) {
                    s1[mt][r] += __shfl_xor(s1[mt][r], o, 64);
                    s2[mt][r] += __shfl_xor(s2[mt][r], o, 64);
                }
            }
        if (fr == 0) {
            #pragma unroll
            for (int mt = 0; mt < 2; mt++)
                #pragma unroll
                for (int r = 0; r < 4; r++) {
                    ssum[mt * 16 + quad * 4 + r][w] = s1[mt][r];
                    ssq [mt * 16 + quad * 4 + r][w] = s2[mt][r];
                }
        }
    }
    __syncthreads();
    {
        #pragma unroll
        for (int mt = 0; mt < 2; mt++) {
            float mu[4], rs[4];
            #pragma unroll
            for (int r = 0; r < 4; r++) {
                int row = mt * 16 + quad * 4 + r;
                float u1 = ssum[row][0] + ssum[row][1] + ssum[row][2] + ssum[row][3];
                float u2 = ssq[row][0] + ssq[row][1] + ssq[row][2] + ssq[row][3];
                mu[r] = u1 * (1.0f / EE);
                float var = u2 * (1.0f / EE) - mu[r] * mu[r];
                rs[r] = rsqrtf(var + 1e-5f);
            }
            #pragma unroll
            for (int nt = 0; nt < 6; nt++) {
                int n = n0 + nt * 16 + fr;
                float gv = g2[n], bev = be2[n];
                #pragma unroll
                for (int r = 0; r < 4; r++)
                    out[(size_t)(m0 + mt * 16 + quad * 4 + r) * EE + n] =
                        (acc[mt][nt][r] - mu[r]) * rs[r] * gv + bev;
            }
        }
    }
}

extern "C" void kernel_launch(void* const* d_in, const int* in_sizes, int n_in,
                              void* d_out, int out_size, void* d_ws, size_t ws_size,
                              hipStream_t stream) {
    (void)in_sizes; (void)n_in; (void)out_size; (void)ws_size;
    const float* x   = (const float*)d_in[0];
    const float* Wq  = (const float*)d_in[1];
    const float* Wo  = (const float*)d_in[2];
    const float* bo  = (const float*)d_in[3];
    const float* W1  = (const float*)d_in[4];
    const float* b1  = (const float*)d_in[5];
    const float* W2  = (const float*)d_in[6];
    const float* b2  = (const float*)d_in[7];
    const float* g1  = (const float*)d_in[8];
    const float* be1 = (const float*)d_in[9];
    const float* g2  = (const float*)d_in[10];
    const float* be2 = (const float*)d_in[11];
    float* out = (float*)d_out;

    float* ws = (float*)d_ws;
    const size_t SZ = (size_t)MM * EE;    // 3,145,728 elems / region (12.6 MB fp32)
    float* S1 = ws + SZ;                   // qbf + qbfT (bf16, fills region exactly)
    float* S2 = ws + 2 * SZ;               // catb (bf16)
    float* S3 = ws + 3 * SZ;               // weight bf16 copies

    unsigned short* qbf  = (unsigned short*)S1;
    unsigned short* qbfT = qbf + (size_t)BB * HH * TT * DD;   // AFTER all of qbf!
    unsigned short* catb = (unsigned short*)S2;
    unsigned short* wqb  = (unsigned short*)S3;
    unsigned short* wob  = wqb + (size_t)EE * EE;
    unsigned short* w1b  = wob + (size_t)EE * EE;
    unsigned short* w2b  = w1b + (size_t)EE * EE;

    k_cvt<<<dim3(4 * 144), dim3(256), 0, stream>>>(Wq, Wo, W1, W2, wqb, wob, w1b, w2b);
    k_qgemm<<<dim3(MM / 16, 2), dim3(256), 0, stream>>>(x, wqb, qbf);
    k_prep<<<dim3(TT / 64, BB * HH), dim3(256), 0, stream>>>(qbf, qbfT);
    k_attn<<<dim3(32, BB * HH), dim3(256), 0, stream>>>(qbf, qbfT, catb);
    k_ffn<<<dim3(MM / 32), dim3(256), 0, stream>>>(catb, wob, bo, x, g1, be1,
                                                   w1b, b1, w2b, b2, g2, be2, out);
}